// Round 1
// baseline (1051.412 us; speedup 1.0000x reference)
//
#include <hip/hip_runtime.h>
#include <math.h>

// Problem constants
#define Bn  16
#define Cn  512
#define Nn  1024     // H*W = 32*32
#define Gn  8
#define CPG 64       // Cn/Gn
#define EPSf 1e-5f

// ---------------------------------------------------------------------------
// Workspace layout (floats):
//   stats : 256                       (mean[128], rstd[128])
//   h     : Bn*Cn*Nn      = 8388608   (groupnorm out; later reused as attn_out)
//   qkv   : Bn*3*Cn*Nn    = 25165824
//   S     : Bn*Nn*Nn      = 16777216
// total ≈ 192 MiB
// ---------------------------------------------------------------------------

__global__ __launch_bounds__(256) void gn_stats_k(const float* __restrict__ x,
                                                  float* __restrict__ stats) {
  int bg = blockIdx.x;  // 0..127 ; group channels are contiguous in memory
  const float4* xp = (const float4*)(x + (size_t)bg * (CPG * Nn));
  float s = 0.f, ss = 0.f;
  const int cnt4 = CPG * Nn / 4;  // 16384
  for (int i = threadIdx.x; i < cnt4; i += 256) {
    float4 v = xp[i];
    s  += v.x + v.y + v.z + v.w;
    ss += v.x*v.x + v.y*v.y + v.z*v.z + v.w*v.w;
  }
  #pragma unroll
  for (int off = 32; off > 0; off >>= 1) {
    s  += __shfl_down(s, off);
    ss += __shfl_down(ss, off);
  }
  __shared__ float sm[4], sq[4];
  int lane = threadIdx.x & 63, wid = threadIdx.x >> 6;
  if (lane == 0) { sm[wid] = s; sq[wid] = ss; }
  __syncthreads();
  if (threadIdx.x == 0) {
    float S  = sm[0] + sm[1] + sm[2] + sm[3];
    float SS = sq[0] + sq[1] + sq[2] + sq[3];
    const float inv = 1.0f / (float)(CPG * Nn);
    float m = S * inv;
    float var = SS * inv - m * m;
    stats[bg]       = m;
    stats[128 + bg] = rsqrtf(var + EPSf);
  }
}

__global__ __launch_bounds__(256) void gn_apply_k(const float* __restrict__ x,
    const float* __restrict__ stats, const float* __restrict__ nw,
    const float* __restrict__ nb, float* __restrict__ h) {
  int i4 = blockIdx.x * 256 + threadIdx.x;  // float4 index, < 2097152
  int r  = i4 >> 8;          // global channel-row index = b*Cn + c  (Nn/4 = 256)
  int c  = r & (Cn - 1);
  int b  = r >> 9;
  int bg = b * Gn + (c >> 6);
  float m  = stats[bg];
  float rs = stats[128 + bg];
  float a  = nw[c] * rs;
  float bb = nb[c] - m * a;
  float4 xv = ((const float4*)x)[i4];
  float4 hv;
  hv.x = xv.x * a + bb; hv.y = xv.y * a + bb;
  hv.z = xv.z * a + bb; hv.w = xv.w * a + bb;
  ((float4*)h)[i4] = hv;
}

// Out[b,m,n] = sum_k W[m,k]*In[b,k,n] + bias[m] (+ resid[b,m,n] if resid)
// 64x64 output tile per block, BK=16, 256 threads, 4x4 per thread.
__global__ __launch_bounds__(256) void gemm_k(const float* __restrict__ W,
    const float* __restrict__ In, const float* __restrict__ bias,
    const float* __restrict__ resid, float* __restrict__ Out, int Mtot) {
  const int K = Cn;
  int b  = blockIdx.z;
  int m0 = blockIdx.y * 64, n0 = blockIdx.x * 64;
  const float* Inb = In + (size_t)b * K * Nn;
  __shared__ float Ws[16][68];  // [k][m]
  __shared__ float Bs[16][68];  // [k][n]
  int t  = threadIdx.x;
  int tx = t & 15, ty = t >> 4;
  int wm = t >> 2, wk = (t & 3) * 4;       // W-tile load: 64 rows x 16 k
  int lk = t >> 4, ln = (t & 15) * 4;      // In-tile load: 16 k x 64 n
  float acc[4][4] = {};
  for (int k0 = 0; k0 < K; k0 += 16) {
    float4 wv = *(const float4*)(W + (size_t)(m0 + wm) * K + k0 + wk);
    Ws[wk + 0][wm] = wv.x; Ws[wk + 1][wm] = wv.y;
    Ws[wk + 2][wm] = wv.z; Ws[wk + 3][wm] = wv.w;
    *(float4*)&Bs[lk][ln] = *(const float4*)(Inb + (size_t)(k0 + lk) * Nn + n0 + ln);
    __syncthreads();
    #pragma unroll
    for (int kk = 0; kk < 16; kk++) {
      float4 a  = *(const float4*)&Ws[kk][ty * 4];
      float4 bv = *(const float4*)&Bs[kk][tx * 4];
      acc[0][0] += a.x*bv.x; acc[0][1] += a.x*bv.y; acc[0][2] += a.x*bv.z; acc[0][3] += a.x*bv.w;
      acc[1][0] += a.y*bv.x; acc[1][1] += a.y*bv.y; acc[1][2] += a.y*bv.z; acc[1][3] += a.y*bv.w;
      acc[2][0] += a.z*bv.x; acc[2][1] += a.z*bv.y; acc[2][2] += a.z*bv.z; acc[2][3] += a.z*bv.w;
      acc[3][0] += a.w*bv.x; acc[3][1] += a.w*bv.y; acc[3][2] += a.w*bv.z; acc[3][3] += a.w*bv.w;
    }
    __syncthreads();
  }
  #pragma unroll
  for (int i = 0; i < 4; i++) {
    int m = m0 + ty * 4 + i;
    float bi = bias[m];
    size_t oi = ((size_t)b * Mtot + m) * Nn + n0 + tx * 4;
    float4 o;
    o.x = acc[i][0] + bi; o.y = acc[i][1] + bi;
    o.z = acc[i][2] + bi; o.w = acc[i][3] + bi;
    if (resid) {
      float4 rv = *(const float4*)(resid + oi);
      o.x += rv.x; o.y += rv.y; o.z += rv.z; o.w += rv.w;
    }
    *(float4*)(Out + oi) = o;
  }
}

// S[b,i,j] = scale * sum_c q[b,c,i]*k[b,c,j]
__global__ __launch_bounds__(256) void qk_k(const float* __restrict__ qkv,
                                            float* __restrict__ S) {
  int b  = blockIdx.z;
  int j0 = blockIdx.x * 64, i0 = blockIdx.y * 64;
  const float* q = qkv + (size_t)b * 3 * Cn * Nn;
  const float* k = q + (size_t)Cn * Nn;
  __shared__ float Qs[16][68], Ks[16][68];  // [c][i] / [c][j]
  int t  = threadIdx.x, tx = t & 15, ty = t >> 4;
  int lc = t >> 4, li = (t & 15) * 4;
  float acc[4][4] = {};
  for (int c0 = 0; c0 < Cn; c0 += 16) {
    *(float4*)&Qs[lc][li] = *(const float4*)(q + (size_t)(c0 + lc) * Nn + i0 + li);
    *(float4*)&Ks[lc][li] = *(const float4*)(k + (size_t)(c0 + lc) * Nn + j0 + li);
    __syncthreads();
    #pragma unroll
    for (int kk = 0; kk < 16; kk++) {
      float4 a  = *(const float4*)&Qs[kk][ty * 4];   // i
      float4 bv = *(const float4*)&Ks[kk][tx * 4];   // j
      acc[0][0] += a.x*bv.x; acc[0][1] += a.x*bv.y; acc[0][2] += a.x*bv.z; acc[0][3] += a.x*bv.w;
      acc[1][0] += a.y*bv.x; acc[1][1] += a.y*bv.y; acc[1][2] += a.y*bv.z; acc[1][3] += a.y*bv.w;
      acc[2][0] += a.z*bv.x; acc[2][1] += a.z*bv.y; acc[2][2] += a.z*bv.z; acc[2][3] += a.z*bv.w;
      acc[3][0] += a.w*bv.x; acc[3][1] += a.w*bv.y; acc[3][2] += a.w*bv.z; acc[3][3] += a.w*bv.w;
    }
    __syncthreads();
  }
  const float scale = 0.04419417382415922f;  // 512^-0.5
  float* Sp = S + ((size_t)b * Nn + i0) * Nn + j0;
  #pragma unroll
  for (int i = 0; i < 4; i++) {
    float4 o;
    o.x = acc[i][0] * scale; o.y = acc[i][1] * scale;
    o.z = acc[i][2] * scale; o.w = acc[i][3] * scale;
    *(float4*)&Sp[(size_t)(ty * 4 + i) * Nn + tx * 4] = o;
  }
}

__global__ __launch_bounds__(256) void softmax_k(float* __restrict__ S) {
  float4* p = (float4*)(S + (size_t)blockIdx.x * Nn);
  int t = threadIdx.x;
  float4 v = p[t];
  float m = fmaxf(fmaxf(v.x, v.y), fmaxf(v.z, v.w));
  #pragma unroll
  for (int off = 1; off < 64; off <<= 1) m = fmaxf(m, __shfl_xor(m, off));
  __shared__ float sm[4], sq[4];
  int lane = t & 63, wid = t >> 6;
  if (lane == 0) sm[wid] = m;
  __syncthreads();
  m = fmaxf(fmaxf(sm[0], sm[1]), fmaxf(sm[2], sm[3]));
  v.x = __expf(v.x - m); v.y = __expf(v.y - m);
  v.z = __expf(v.z - m); v.w = __expf(v.w - m);
  float s = v.x + v.y + v.z + v.w;
  #pragma unroll
  for (int off = 1; off < 64; off <<= 1) s += __shfl_xor(s, off);
  if (lane == 0) sq[wid] = s;
  __syncthreads();
  s = sq[0] + sq[1] + sq[2] + sq[3];
  float r = 1.0f / s;
  v.x *= r; v.y *= r; v.z *= r; v.w *= r;
  p[t] = v;
}

// out[b,c,i] = sum_j S[b,i,j] * v[b,c,j]
__global__ __launch_bounds__(256) void pv_k(const float* __restrict__ qkv,
    const float* __restrict__ S, float* __restrict__ out) {
  int b  = blockIdx.z;
  int i0 = blockIdx.x * 64, c0 = blockIdx.y * 64;
  const float* v  = qkv + (size_t)b * 3 * Cn * Nn + 2 * (size_t)Cn * Nn;
  const float* Sb = S + (size_t)b * Nn * Nn;
  __shared__ float Vs[16][68];  // [j][c]
  __shared__ float Ss[16][68];  // [j][i]
  int t = threadIdx.x, tx = t & 15, ty = t >> 4;
  int rr = t >> 2, jj = (t & 3) * 4;
  float acc[4][4] = {};
  for (int j0 = 0; j0 < Nn; j0 += 16) {
    float4 vv = *(const float4*)(v + (size_t)(c0 + rr) * Nn + j0 + jj);
    Vs[jj + 0][rr] = vv.x; Vs[jj + 1][rr] = vv.y;
    Vs[jj + 2][rr] = vv.z; Vs[jj + 3][rr] = vv.w;
    float4 sv = *(const float4*)(Sb + (size_t)(i0 + rr) * Nn + j0 + jj);
    Ss[jj + 0][rr] = sv.x; Ss[jj + 1][rr] = sv.y;
    Ss[jj + 2][rr] = sv.z; Ss[jj + 3][rr] = sv.w;
    __syncthreads();
    #pragma unroll
    for (int kk = 0; kk < 16; kk++) {
      float4 a  = *(const float4*)&Vs[kk][ty * 4];   // channels
      float4 bv = *(const float4*)&Ss[kk][tx * 4];   // tokens
      acc[0][0] += a.x*bv.x; acc[0][1] += a.x*bv.y; acc[0][2] += a.x*bv.z; acc[0][3] += a.x*bv.w;
      acc[1][0] += a.y*bv.x; acc[1][1] += a.y*bv.y; acc[1][2] += a.y*bv.z; acc[1][3] += a.y*bv.w;
      acc[2][0] += a.z*bv.x; acc[2][1] += a.z*bv.y; acc[2][2] += a.z*bv.z; acc[2][3] += a.z*bv.w;
      acc[3][0] += a.w*bv.x; acc[3][1] += a.w*bv.y; acc[3][2] += a.w*bv.z; acc[3][3] += a.w*bv.w;
    }
    __syncthreads();
  }
  #pragma unroll
  for (int i = 0; i < 4; i++) {
    int c = c0 + ty * 4 + i;
    size_t oi = ((size_t)b * Cn + c) * Nn + i0 + tx * 4;
    float4 o;
    o.x = acc[i][0]; o.y = acc[i][1]; o.z = acc[i][2]; o.w = acc[i][3];
    *(float4*)(out + oi) = o;
  }
}

extern "C" void kernel_launch(void* const* d_in, const int* in_sizes, int n_in,
                              void* d_out, int out_size, void* d_ws, size_t ws_size,
                              hipStream_t stream) {
  const float* x      = (const float*)d_in[0];
  const float* norm_w = (const float*)d_in[1];
  const float* norm_b = (const float*)d_in[2];
  const float* qkv_w  = (const float*)d_in[3];
  const float* qkv_b  = (const float*)d_in[4];
  const float* proj_w = (const float*)d_in[5];
  const float* proj_b = (const float*)d_in[6];
  float* out = (float*)d_out;
  float* ws  = (float*)d_ws;

  float* stats = ws;                            // 256 floats
  float* h     = ws + 256;                      // B*C*N (reused as attn_out)
  float* qkv   = h + (size_t)Bn * Cn * Nn;      // B*3C*N
  float* S     = qkv + (size_t)Bn * 3 * Cn * Nn;// B*N*N

  gn_stats_k<<<Bn * Gn, 256, 0, stream>>>(x, stats);
  gn_apply_k<<<(Bn * Cn * Nn / 4) / 256, 256, 0, stream>>>(x, stats, norm_w, norm_b, h);
  gemm_k<<<dim3(Nn / 64, 3 * Cn / 64, Bn), 256, 0, stream>>>(qkv_w, h, qkv_b, nullptr, qkv, 3 * Cn);
  qk_k<<<dim3(Nn / 64, Nn / 64, Bn), 256, 0, stream>>>(qkv, S);
  softmax_k<<<Bn * Nn, 256, 0, stream>>>(S);
  pv_k<<<dim3(Nn / 64, Cn / 64, Bn), 256, 0, stream>>>(qkv, S, h);
  gemm_k<<<dim3(Nn / 64, Cn / 64, Bn), 256, 0, stream>>>(proj_w, h, proj_b, x, out, Cn);
}

// Round 2
// 288.050 us; speedup vs baseline: 3.6501x; 3.6501x over previous
//
#include <hip/hip_runtime.h>
#include <math.h>

#define Bn  16
#define Cn  512
#define Nn  1024
#define Gn  8
#define CPG 64
#define EPSf 1e-5f

typedef short           bf16x8 __attribute__((ext_vector_type(8)));
typedef float           f32x4  __attribute__((ext_vector_type(4)));
typedef unsigned short  u16;
typedef unsigned short  u16x4  __attribute__((ext_vector_type(4)));
typedef unsigned short  u16x8  __attribute__((ext_vector_type(8)));

#define LDST 40   // LDS row stride in bf16 units: 80 B = 20 banks -> 2-way max (free)

__device__ __forceinline__ u16 f2b(float f) {
  union { float f; unsigned u; } c; c.f = f;
  unsigned r = (c.u + 0x7FFFu + ((c.u >> 16) & 1u)) >> 16;
  return (u16)r;
}

// ---------------------------------------------------------------------------
// GroupNorm stats: one block per (b, group)
__global__ __launch_bounds__(256) void gn_stats_k(const float* __restrict__ x,
                                                  float* __restrict__ stats) {
  int bg = blockIdx.x;
  const float4* xp = (const float4*)(x + (size_t)bg * (CPG * Nn));
  float s = 0.f, ss = 0.f;
  const int cnt4 = CPG * Nn / 4;
  for (int i = threadIdx.x; i < cnt4; i += 256) {
    float4 v = xp[i];
    s  += v.x + v.y + v.z + v.w;
    ss += v.x*v.x + v.y*v.y + v.z*v.z + v.w*v.w;
  }
  #pragma unroll
  for (int off = 32; off > 0; off >>= 1) {
    s  += __shfl_down(s, off);
    ss += __shfl_down(ss, off);
  }
  __shared__ float sm[4], sq[4];
  int lane = threadIdx.x & 63, wid = threadIdx.x >> 6;
  if (lane == 0) { sm[wid] = s; sq[wid] = ss; }
  __syncthreads();
  if (threadIdx.x == 0) {
    float S  = sm[0] + sm[1] + sm[2] + sm[3];
    float SS = sq[0] + sq[1] + sq[2] + sq[3];
    const float inv = 1.0f / (float)(CPG * Nn);
    float m = S * inv;
    float var = SS * inv - m * m;
    stats[bg]       = m;
    stats[128 + bg] = rsqrtf(var + EPSf);
  }
}

// ---------------------------------------------------------------------------
// GroupNorm apply + transpose: x[b][c][n] fp32 -> hT[b][n][c] bf16
// block handles 64c x 64n tile; grid (N/64, C/64, B)
__global__ __launch_bounds__(256) void gn_apply_t_k(const float* __restrict__ x,
    const float* __restrict__ stats, const float* __restrict__ nw,
    const float* __restrict__ nb, u16* __restrict__ hT) {
  int b = blockIdx.z, c0 = blockIdx.y * 64, n0 = blockIdx.x * 64;
  __shared__ u16 T[64][68];
  int t = threadIdx.x;
  int row = t >> 4, col4 = t & 15;
  #pragma unroll
  for (int it = 0; it < 4; it++) {
    int cc = row + it * 16;
    int c  = c0 + cc;
    int bg = b * Gn + (c >> 6);
    float mean = stats[bg], rs = stats[128 + bg];
    float a  = nw[c] * rs;
    float bb = nb[c] - mean * a;
    float4 xv = *(const float4*)&x[((size_t)(b * Cn + c)) * Nn + n0 + col4 * 4];
    u16x4 o;
    o.x = f2b(xv.x * a + bb); o.y = f2b(xv.y * a + bb);
    o.z = f2b(xv.z * a + bb); o.w = f2b(xv.w * a + bb);
    *(u16x4*)&T[cc][col4 * 4] = o;
  }
  __syncthreads();
  #pragma unroll
  for (int it = 0; it < 2; it++) {
    int ch = t + it * 256;
    int n  = ch >> 3, c8 = (ch & 7) * 8;
    u16x8 o;
    #pragma unroll
    for (int j = 0; j < 8; j++) o[j] = T[c8 + j][n];
    *(u16x8*)&hT[((size_t)(b * Nn + n0 + n)) * Cn + c0 + c8] = o;
  }
}

// ---------------------------------------------------------------------------
// fp32 -> bf16 elementwise (weights)
__global__ __launch_bounds__(256) void cvt_k(const float* __restrict__ src,
                                             u16* __restrict__ dst) {
  int i = blockIdx.x * 256 + threadIdx.x;
  float4 v = ((const float4*)src)[i];
  u16x4 o;
  o.x = f2b(v.x); o.y = f2b(v.y); o.z = f2b(v.z); o.w = f2b(v.w);
  ((u16x4*)dst)[i] = o;
}

// ---------------------------------------------------------------------------
// Shared GEMM core: D[128m x 128n] = A[128 x K] * B'[128 x K]^T, both bf16
// row-major with row strides sA/sB (in elements). 256 threads = 4 waves,
// each wave 64x64 via 4x4 frags of mfma_f32_16x16x32_bf16.
__device__ __forceinline__ void gemm_core(const u16* __restrict__ A, size_t sA,
                                          const u16* __restrict__ B, size_t sB,
                                          int K, f32x4 acc[4][4]) {
  __shared__ u16 As[128 * LDST];
  __shared__ u16 Bs[128 * LDST];
  const int t = threadIdx.x;
  const int w = t >> 6, l = t & 63, quad = l >> 4, lr = l & 15;
  const int wm = (w >> 1) * 64, wn = (w & 1) * 64;
  const int r0 = t >> 2, kc = (t & 3) * 8;  // staging chunk (16B) coords

  for (int k0 = 0; k0 < K; k0 += 32) {
    uint4 ga0 = *(const uint4*)(A + (size_t)r0        * sA + k0 + kc);
    uint4 ga1 = *(const uint4*)(A + (size_t)(r0 + 64) * sA + k0 + kc);
    uint4 gb0 = *(const uint4*)(B + (size_t)r0        * sB + k0 + kc);
    uint4 gb1 = *(const uint4*)(B + (size_t)(r0 + 64) * sB + k0 + kc);
    __syncthreads();
    *(uint4*)&As[r0 * LDST + kc]        = ga0;
    *(uint4*)&As[(r0 + 64) * LDST + kc] = ga1;
    *(uint4*)&Bs[r0 * LDST + kc]        = gb0;
    *(uint4*)&Bs[(r0 + 64) * LDST + kc] = gb1;
    __syncthreads();
    bf16x8 af[4], bfr[4];
    #pragma unroll
    for (int fm = 0; fm < 4; fm++)
      af[fm] = *(const bf16x8*)&As[(wm + fm * 16 + lr) * LDST + quad * 8];
    #pragma unroll
    for (int fn = 0; fn < 4; fn++)
      bfr[fn] = *(const bf16x8*)&Bs[(wn + fn * 16 + lr) * LDST + quad * 8];
    #pragma unroll
    for (int fm = 0; fm < 4; fm++)
      #pragma unroll
      for (int fn = 0; fn < 4; fn++)
        acc[fm][fn] = __builtin_amdgcn_mfma_f32_16x16x32_bf16(
            af[fm], bfr[fn], acc[fm][fn], 0, 0, 0);
  }
}

#define GEMM_PRE()                                              \
  const int t = threadIdx.x;                                    \
  const int w = t >> 6, l = t & 63, quad = l >> 4, lr = l & 15; \
  const int wm = (w >> 1) * 64, wn = (w & 1) * 64;              \
  f32x4 acc[4][4];                                              \
  { f32x4 z = {0.f, 0.f, 0.f, 0.f};                             \
    for (int i = 0; i < 4; i++)                                 \
      for (int j = 0; j < 4; j++) acc[i][j] = z; }

// QKV: D[m][n] = qkv_w[m][:] . hT[n][:] + qkv_b[m]
// m<1024 (q,k): store transposed qkT[b][n][m] bf16 (vector)
// m>=1024 (v): store natural v[b][m-1024][n] bf16
__global__ __launch_bounds__(256) void gemm_qkv_k(const u16* __restrict__ w16,
    const u16* __restrict__ hT, const float* __restrict__ bias,
    u16* __restrict__ qkT, u16* __restrict__ v) {
  int b = blockIdx.z, m0 = blockIdx.y * 128, n0 = blockIdx.x * 128;
  GEMM_PRE();
  gemm_core(w16 + (size_t)m0 * Cn, Cn,
            hT + ((size_t)b * Nn + n0) * Cn, Cn, Cn, acc);
  #pragma unroll
  for (int fm = 0; fm < 4; fm++) {
    int mb = m0 + wm + fm * 16 + quad * 4;
    float b0 = bias[mb], b1 = bias[mb + 1], b2 = bias[mb + 2], b3 = bias[mb + 3];
    #pragma unroll
    for (int fn = 0; fn < 4; fn++) {
      int n = n0 + wn + fn * 16 + lr;
      f32x4 a = acc[fm][fn];
      if (m0 < 1024) {
        u16x4 o;
        o.x = f2b(a[0] + b0); o.y = f2b(a[1] + b1);
        o.z = f2b(a[2] + b2); o.w = f2b(a[3] + b3);
        *(u16x4*)&qkT[((size_t)(b * Nn + n)) * 1024 + mb] = o;
      } else {
        int c = mb - 1024;
        v[((size_t)(b * Cn + c    )) * Nn + n] = f2b(a[0] + b0);
        v[((size_t)(b * Cn + c + 1)) * Nn + n] = f2b(a[1] + b1);
        v[((size_t)(b * Cn + c + 2)) * Nn + n] = f2b(a[2] + b2);
        v[((size_t)(b * Cn + c + 3)) * Nn + n] = f2b(a[3] + b3);
      }
    }
  }
}

// QK^T: S[b][i][j] = scale * q[i][:] . k[j][:]   (q,k rows of qkT)
__global__ __launch_bounds__(256) void gemm_qk_k(const u16* __restrict__ qkT,
                                                 float* __restrict__ S) {
  int b = blockIdx.z, i0 = blockIdx.y * 128, j0 = blockIdx.x * 128;
  const u16* base = qkT + (size_t)b * Nn * 1024;
  GEMM_PRE();
  gemm_core(base + (size_t)i0 * 1024, 1024,
            base + (size_t)j0 * 1024 + 512, 1024, Cn, acc);
  const float scale = 0.04419417382415922f;
  #pragma unroll
  for (int fm = 0; fm < 4; fm++) {
    int ib = i0 + wm + fm * 16 + quad * 4;
    #pragma unroll
    for (int fn = 0; fn < 4; fn++) {
      int j = j0 + wn + fn * 16 + lr;
      f32x4 a = acc[fm][fn];
      float* Sp = S + ((size_t)(b * Nn + ib)) * Nn + j;
      Sp[0]          = a[0] * scale;
      Sp[Nn]         = a[1] * scale;
      Sp[2 * Nn]     = a[2] * scale;
      Sp[3 * (size_t)Nn] = a[3] * scale;
    }
  }
}

// softmax row (fp32 in) -> P bf16
__global__ __launch_bounds__(256) void softmax_k(const float* __restrict__ S,
                                                 u16* __restrict__ P) {
  const float4* p = (const float4*)(S + (size_t)blockIdx.x * Nn);
  int t = threadIdx.x;
  float4 v = p[t];
  float m = fmaxf(fmaxf(v.x, v.y), fmaxf(v.z, v.w));
  #pragma unroll
  for (int off = 1; off < 64; off <<= 1) m = fmaxf(m, __shfl_xor(m, off));
  __shared__ float sm[4], sq[4];
  int lane = t & 63, wid = t >> 6;
  if (lane == 0) sm[wid] = m;
  __syncthreads();
  m = fmaxf(fmaxf(sm[0], sm[1]), fmaxf(sm[2], sm[3]));
  v.x = __expf(v.x - m); v.y = __expf(v.y - m);
  v.z = __expf(v.z - m); v.w = __expf(v.w - m);
  float s = v.x + v.y + v.z + v.w;
  #pragma unroll
  for (int off = 1; off < 64; off <<= 1) s += __shfl_xor(s, off);
  if (lane == 0) sq[wid] = s;
  __syncthreads();
  s = sq[0] + sq[1] + sq[2] + sq[3];
  float r = 1.0f / s;
  u16x4 o;
  o.x = f2b(v.x * r); o.y = f2b(v.y * r);
  o.z = f2b(v.z * r); o.w = f2b(v.w * r);
  *(u16x4*)&P[(size_t)blockIdx.x * Nn + t * 4] = o;
}

// PV: O[b][i][c] = P[i][:] . v[c][:]   (A=P rows i, B'=v rows c, K=N)
__global__ __launch_bounds__(256) void gemm_pv_k(const u16* __restrict__ P,
    const u16* __restrict__ v, u16* __restrict__ O) {
  int b = blockIdx.z, i0 = blockIdx.y * 128, c0 = blockIdx.x * 128;
  GEMM_PRE();
  gemm_core(P + ((size_t)b * Nn + i0) * Nn, Nn,
            v + ((size_t)b * Cn + c0) * Nn, Nn, Nn, acc);
  #pragma unroll
  for (int fm = 0; fm < 4; fm++) {
    int ib = i0 + wm + fm * 16 + quad * 4;
    #pragma unroll
    for (int fn = 0; fn < 4; fn++) {
      int c = c0 + wn + fn * 16 + lr;
      f32x4 a = acc[fm][fn];
      O[((size_t)(b * Nn + ib    )) * Cn + c] = f2b(a[0]);
      O[((size_t)(b * Nn + ib + 1)) * Cn + c] = f2b(a[1]);
      O[((size_t)(b * Nn + ib + 2)) * Cn + c] = f2b(a[2]);
      O[((size_t)(b * Nn + ib + 3)) * Cn + c] = f2b(a[3]);
    }
  }
}

// proj: out[b][m][n] = proj_w[m][:] . O[n][:] + proj_b[m] + x[b][m][n]
__global__ __launch_bounds__(256) void gemm_proj_k(const u16* __restrict__ pw16,
    const u16* __restrict__ O, const float* __restrict__ bias,
    const float* __restrict__ x, float* __restrict__ out) {
  int b = blockIdx.z, m0 = blockIdx.y * 128, n0 = blockIdx.x * 128;
  GEMM_PRE();
  gemm_core(pw16 + (size_t)m0 * Cn, Cn,
            O + ((size_t)b * Nn + n0) * Cn, Cn, Cn, acc);
  #pragma unroll
  for (int fm = 0; fm < 4; fm++) {
    int mb = m0 + wm + fm * 16 + quad * 4;
    #pragma unroll
    for (int fn = 0; fn < 4; fn++) {
      int n = n0 + wn + fn * 16 + lr;
      f32x4 a = acc[fm][fn];
      #pragma unroll
      for (int r = 0; r < 4; r++) {
        size_t oi = ((size_t)(b * Cn + mb + r)) * Nn + n;
        out[oi] = a[r] + bias[mb + r] + x[oi];
      }
    }
  }
}

// ---------------------------------------------------------------------------
extern "C" void kernel_launch(void* const* d_in, const int* in_sizes, int n_in,
                              void* d_out, int out_size, void* d_ws, size_t ws_size,
                              hipStream_t stream) {
  const float* x      = (const float*)d_in[0];
  const float* norm_w = (const float*)d_in[1];
  const float* norm_b = (const float*)d_in[2];
  const float* qkv_w  = (const float*)d_in[3];
  const float* qkv_b  = (const float*)d_in[4];
  const float* proj_w = (const float*)d_in[5];
  const float* proj_b = (const float*)d_in[6];
  float* out = (float*)d_out;
  char* ws = (char*)d_ws;

  u16*   wq16  = (u16*)(ws);                       // 1536*512
  u16*   wp16  = (u16*)(ws + 1572864);             // 512*512
  u16*   hT    = (u16*)(ws + 2097152);             // B*N*C
  u16*   qkT   = (u16*)(ws + 18874368);            // B*N*1024
  u16*   v     = (u16*)(ws + 52428800);            // B*C*N
  float* S     = (float*)(ws + 69206016);          // B*N*N fp32
  u16*   P     = (u16*)(ws + 136314880);           // B*N*N
  u16*   O     = (u16*)(ws + 169869312);           // B*N*C
  float* stats = (float*)(ws + 186646528);         // 256

  cvt_k<<<768, 256, 0, stream>>>(qkv_w, wq16);
  cvt_k<<<256, 256, 0, stream>>>(proj_w, wp16);
  gn_stats_k<<<Bn * Gn, 256, 0, stream>>>(x, stats);
  gn_apply_t_k<<<dim3(Nn / 64, Cn / 64, Bn), 256, 0, stream>>>(x, stats, norm_w, norm_b, hT);
  gemm_qkv_k<<<dim3(Nn / 128, 1536 / 128, Bn), 256, 0, stream>>>(wq16, hT, qkv_b, qkT, v);
  gemm_qk_k<<<dim3(Nn / 128, Nn / 128, Bn), 256, 0, stream>>>(qkT, S);
  softmax_k<<<Bn * Nn, 256, 0, stream>>>(S, P);
  gemm_pv_k<<<dim3(Cn / 128, Nn / 128, Bn), 256, 0, stream>>>(P, v, O);
  gemm_proj_k<<<dim3(Nn / 128, Cn / 128, Bn), 256, 0, stream>>>(wp16, O, proj_b, x, out);
}

// Round 3
// 276.741 us; speedup vs baseline: 3.7993x; 1.0409x over previous
//
#include <hip/hip_runtime.h>
#include <math.h>

#define Bn  16
#define Cn  512
#define Nn  1024
#define Gn  8
#define CPG 64
#define EPSf 1e-5f

typedef short           bf16x8 __attribute__((ext_vector_type(8)));
typedef float           f32x4  __attribute__((ext_vector_type(4)));
typedef unsigned short  u16;
typedef unsigned short  u16x4  __attribute__((ext_vector_type(4)));
typedef unsigned short  u16x8  __attribute__((ext_vector_type(8)));

__device__ __forceinline__ u16 f2b(float f) {
  union { float f; unsigned u; } c; c.f = f;
  unsigned r = (c.u + 0x7FFFu + ((c.u >> 16) & 1u)) >> 16;
  return (u16)r;
}

// async 16B global -> LDS DMA (dest = wave base + lane*16, no padding allowed)
__device__ __forceinline__ void g2l16(const void* g, void* l) {
  __builtin_amdgcn_global_load_lds(
      (const __attribute__((address_space(1))) unsigned int*)g,
      (__attribute__((address_space(3))) unsigned int*)l, 16, 0, 0);
}

// ---------------------------------------------------------------------------
__global__ __launch_bounds__(256) void gn_stats_k(const float* __restrict__ x,
                                                  float* __restrict__ stats) {
  int bg = blockIdx.x;
  const float4* xp = (const float4*)(x + (size_t)bg * (CPG * Nn));
  float s = 0.f, ss = 0.f;
  const int cnt4 = CPG * Nn / 4;
  for (int i = threadIdx.x; i < cnt4; i += 256) {
    float4 v = xp[i];
    s  += v.x + v.y + v.z + v.w;
    ss += v.x*v.x + v.y*v.y + v.z*v.z + v.w*v.w;
  }
  #pragma unroll
  for (int off = 32; off > 0; off >>= 1) {
    s  += __shfl_down(s, off);
    ss += __shfl_down(ss, off);
  }
  __shared__ float sm[4], sq[4];
  int lane = threadIdx.x & 63, wid = threadIdx.x >> 6;
  if (lane == 0) { sm[wid] = s; sq[wid] = ss; }
  __syncthreads();
  if (threadIdx.x == 0) {
    float S  = sm[0] + sm[1] + sm[2] + sm[3];
    float SS = sq[0] + sq[1] + sq[2] + sq[3];
    const float inv = 1.0f / (float)(CPG * Nn);
    float m = S * inv;
    float var = SS * inv - m * m;
    stats[bg]       = m;
    stats[128 + bg] = rsqrtf(var + EPSf);
  }
}

// GroupNorm apply + transpose: x[b][c][n] fp32 -> hT[b][n][c] bf16
__global__ __launch_bounds__(256) void gn_apply_t_k(const float* __restrict__ x,
    const float* __restrict__ stats, const float* __restrict__ nw,
    const float* __restrict__ nb, u16* __restrict__ hT) {
  int b = blockIdx.z, c0 = blockIdx.y * 64, n0 = blockIdx.x * 64;
  __shared__ u16 T[64][68];
  int t = threadIdx.x;
  int row = t >> 4, col4 = t & 15;
  #pragma unroll
  for (int it = 0; it < 4; it++) {
    int cc = row + it * 16;
    int c  = c0 + cc;
    int bg = b * Gn + (c >> 6);
    float mean = stats[bg], rs = stats[128 + bg];
    float a  = nw[c] * rs;
    float bb = nb[c] - mean * a;
    float4 xv = *(const float4*)&x[((size_t)(b * Cn + c)) * Nn + n0 + col4 * 4];
    u16x4 o;
    o.x = f2b(xv.x * a + bb); o.y = f2b(xv.y * a + bb);
    o.z = f2b(xv.z * a + bb); o.w = f2b(xv.w * a + bb);
    *(u16x4*)&T[cc][col4 * 4] = o;
  }
  __syncthreads();
  #pragma unroll
  for (int it = 0; it < 2; it++) {
    int ch = t + it * 256;
    int n  = ch >> 3, c8 = (ch & 7) * 8;
    u16x8 o;
    #pragma unroll
    for (int j = 0; j < 8; j++) o[j] = T[c8 + j][n];
    *(u16x8*)&hT[((size_t)(b * Nn + n0 + n)) * Cn + c0 + c8] = o;
  }
}

__global__ __launch_bounds__(256) void cvt_k(const float* __restrict__ src,
                                             u16* __restrict__ dst) {
  int i = blockIdx.x * 256 + threadIdx.x;
  float4 v = ((const float4*)src)[i];
  u16x4 o;
  o.x = f2b(v.x); o.y = f2b(v.y); o.z = f2b(v.z); o.w = f2b(v.w);
  ((u16x4*)dst)[i] = o;
}

// ---------------------------------------------------------------------------
// GEMM core: D[128x128] = A[128xK] * B'[128xK]^T, bf16, row strides sA/sB.
// global_load_lds width-16 staging; LDS unpadded 32-elem rows with chunk XOR
// swizzle: slot p of row r holds global chunk q = p ^ ((r>>1)&3) -> fragment
// ds_read_b128 lands 2-way max per bank group (free).
__device__ __forceinline__ void gemm_core(const u16* __restrict__ A, size_t sA,
                                          const u16* __restrict__ B, size_t sB,
                                          int K, f32x4 acc[4][4]) {
  __shared__ u16 As[128 * 32];
  __shared__ u16 Bs[128 * 32];
  const int t = threadIdx.x;
  const int w = t >> 6, l = t & 63, quad = l >> 4, lr = l & 15;
  const int wm = (w >> 1) * 64, wn = (w & 1) * 64;

  // staging: wave w covers rows [w*16, w*16+16) and +64; lane l -> row + l>>2,
  // LDS slot p = l&3, global chunk q = p ^ f(row)   (f(row+64) == f(row))
  const int ra = w * 16 + (l >> 2);
  const int p  = l & 3;
  const int q  = p ^ ((ra >> 1) & 3);
  const u16* gA0 = A + (size_t)ra * sA + q * 8;
  const u16* gA1 = A + (size_t)(ra + 64) * sA + q * 8;
  const u16* gB0 = B + (size_t)ra * sB + q * 8;
  const u16* gB1 = B + (size_t)(ra + 64) * sB + q * 8;
  u16* lA0 = As + ra * 32 + p * 8;
  u16* lA1 = As + (ra + 64) * 32 + p * 8;
  u16* lB0 = Bs + ra * 32 + p * 8;
  u16* lB1 = Bs + (ra + 64) * 32 + p * 8;

  for (int k0 = 0; k0 < K; k0 += 32) {
    __syncthreads();                      // previous iter's reads complete
    g2l16(gA0 + k0, lA0);
    g2l16(gA1 + k0, lA1);
    g2l16(gB0 + k0, lB0);
    g2l16(gB1 + k0, lB1);
    __syncthreads();                      // drains vmcnt before reads
    bf16x8 af[4], bfr[4];
    #pragma unroll
    for (int fm = 0; fm < 4; fm++) {
      int r = wm + fm * 16 + lr;
      af[fm] = *(const bf16x8*)&As[r * 32 + ((quad ^ ((r >> 1) & 3)) << 3)];
    }
    #pragma unroll
    for (int fn = 0; fn < 4; fn++) {
      int r = wn + fn * 16 + lr;
      bfr[fn] = *(const bf16x8*)&Bs[r * 32 + ((quad ^ ((r >> 1) & 3)) << 3)];
    }
    #pragma unroll
    for (int fm = 0; fm < 4; fm++)
      #pragma unroll
      for (int fn = 0; fn < 4; fn++)
        acc[fm][fn] = __builtin_amdgcn_mfma_f32_16x16x32_bf16(
            af[fm], bfr[fn], acc[fm][fn], 0, 0, 0);
  }
}

#define GEMM_PRE()                                              \
  const int t = threadIdx.x;                                    \
  const int w = t >> 6, l = t & 63, quad = l >> 4, lr = l & 15; \
  const int wm = (w >> 1) * 64, wn = (w & 1) * 64;              \
  f32x4 acc[4][4];                                              \
  { f32x4 z = {0.f, 0.f, 0.f, 0.f};                             \
    for (int i = 0; i < 4; i++)                                 \
      for (int j = 0; j < 4; j++) acc[i][j] = z; }

__global__ __launch_bounds__(256) void gemm_qkv_k(const u16* __restrict__ w16,
    const u16* __restrict__ hT, const float* __restrict__ bias,
    u16* __restrict__ qkT, u16* __restrict__ v) {
  int b = blockIdx.z, m0 = blockIdx.y * 128, n0 = blockIdx.x * 128;
  GEMM_PRE();
  gemm_core(w16 + (size_t)m0 * Cn, Cn,
            hT + ((size_t)b * Nn + n0) * Cn, Cn, Cn, acc);
  #pragma unroll
  for (int fm = 0; fm < 4; fm++) {
    int mb = m0 + wm + fm * 16 + quad * 4;
    float b0 = bias[mb], b1 = bias[mb + 1], b2 = bias[mb + 2], b3 = bias[mb + 3];
    #pragma unroll
    for (int fn = 0; fn < 4; fn++) {
      int n = n0 + wn + fn * 16 + lr;
      f32x4 a = acc[fm][fn];
      if (m0 < 1024) {
        u16x4 o;
        o.x = f2b(a[0] + b0); o.y = f2b(a[1] + b1);
        o.z = f2b(a[2] + b2); o.w = f2b(a[3] + b3);
        *(u16x4*)&qkT[((size_t)(b * Nn + n)) * 1024 + mb] = o;
      } else {
        int c = mb - 1024;
        v[((size_t)(b * Cn + c    )) * Nn + n] = f2b(a[0] + b0);
        v[((size_t)(b * Cn + c + 1)) * Nn + n] = f2b(a[1] + b1);
        v[((size_t)(b * Cn + c + 2)) * Nn + n] = f2b(a[2] + b2);
        v[((size_t)(b * Cn + c + 3)) * Nn + n] = f2b(a[3] + b3);
      }
    }
  }
}

__global__ __launch_bounds__(256) void gemm_qk_k(const u16* __restrict__ qkT,
                                                 float* __restrict__ S) {
  int b = blockIdx.z, i0 = blockIdx.y * 128, j0 = blockIdx.x * 128;
  const u16* base = qkT + (size_t)b * Nn * 1024;
  GEMM_PRE();
  gemm_core(base + (size_t)i0 * 1024, 1024,
            base + (size_t)j0 * 1024 + 512, 1024, Cn, acc);
  const float scale = 0.04419417382415922f;
  #pragma unroll
  for (int fm = 0; fm < 4; fm++) {
    int ib = i0 + wm + fm * 16 + quad * 4;
    #pragma unroll
    for (int fn = 0; fn < 4; fn++) {
      int j = j0 + wn + fn * 16 + lr;
      f32x4 a = acc[fm][fn];
      float* Sp = S + ((size_t)(b * Nn + ib)) * Nn + j;
      Sp[0]              = a[0] * scale;
      Sp[Nn]             = a[1] * scale;
      Sp[2 * Nn]         = a[2] * scale;
      Sp[3 * (size_t)Nn] = a[3] * scale;
    }
  }
}

__global__ __launch_bounds__(256) void softmax_k(const float* __restrict__ S,
                                                 u16* __restrict__ P) {
  const float4* p = (const float4*)(S + (size_t)blockIdx.x * Nn);
  int t = threadIdx.x;
  float4 v = p[t];
  float m = fmaxf(fmaxf(v.x, v.y), fmaxf(v.z, v.w));
  #pragma unroll
  for (int off = 1; off < 64; off <<= 1) m = fmaxf(m, __shfl_xor(m, off));
  __shared__ float sm[4], sq[4];
  int lane = t & 63, wid = t >> 6;
  if (lane == 0) sm[wid] = m;
  __syncthreads();
  m = fmaxf(fmaxf(sm[0], sm[1]), fmaxf(sm[2], sm[3]));
  v.x = __expf(v.x - m); v.y = __expf(v.y - m);
  v.z = __expf(v.z - m); v.w = __expf(v.w - m);
  float s = v.x + v.y + v.z + v.w;
  #pragma unroll
  for (int off = 1; off < 64; off <<= 1) s += __shfl_xor(s, off);
  if (lane == 0) sq[wid] = s;
  __syncthreads();
  s = sq[0] + sq[1] + sq[2] + sq[3];
  float r = 1.0f / s;
  u16x4 o;
  o.x = f2b(v.x * r); o.y = f2b(v.y * r);
  o.z = f2b(v.z * r); o.w = f2b(v.w * r);
  *(u16x4*)&P[(size_t)blockIdx.x * Nn + t * 4] = o;
}

__global__ __launch_bounds__(256) void gemm_pv_k(const u16* __restrict__ P,
    const u16* __restrict__ v, u16* __restrict__ O) {
  int b = blockIdx.z, i0 = blockIdx.y * 128, c0 = blockIdx.x * 128;
  GEMM_PRE();
  gemm_core(P + ((size_t)b * Nn + i0) * Nn, Nn,
            v + ((size_t)b * Cn + c0) * Nn, Nn, Nn, acc);
  #pragma unroll
  for (int fm = 0; fm < 4; fm++) {
    int ib = i0 + wm + fm * 16 + quad * 4;
    #pragma unroll
    for (int fn = 0; fn < 4; fn++) {
      int c = c0 + wn + fn * 16 + lr;
      f32x4 a = acc[fm][fn];
      O[((size_t)(b * Nn + ib    )) * Cn + c] = f2b(a[0]);
      O[((size_t)(b * Nn + ib + 1)) * Cn + c] = f2b(a[1]);
      O[((size_t)(b * Nn + ib + 2)) * Cn + c] = f2b(a[2]);
      O[((size_t)(b * Nn + ib + 3)) * Cn + c] = f2b(a[3]);
    }
  }
}

__global__ __launch_bounds__(256) void gemm_proj_k(const u16* __restrict__ pw16,
    const u16* __restrict__ O, const float* __restrict__ bias,
    const float* __restrict__ x, float* __restrict__ out) {
  int b = blockIdx.z, m0 = blockIdx.y * 128, n0 = blockIdx.x * 128;
  GEMM_PRE();
  gemm_core(pw16 + (size_t)m0 * Cn, Cn,
            O + ((size_t)b * Nn + n0) * Cn, Cn, Cn, acc);
  #pragma unroll
  for (int fm = 0; fm < 4; fm++) {
    int mb = m0 + wm + fm * 16 + quad * 4;
    #pragma unroll
    for (int fn = 0; fn < 4; fn++) {
      int n = n0 + wn + fn * 16 + lr;
      f32x4 a = acc[fm][fn];
      #pragma unroll
      for (int r = 0; r < 4; r++) {
        size_t oi = ((size_t)(b * Cn + mb + r)) * Nn + n;
        out[oi] = a[r] + bias[mb + r] + x[oi];
      }
    }
  }
}

// ---------------------------------------------------------------------------
extern "C" void kernel_launch(void* const* d_in, const int* in_sizes, int n_in,
                              void* d_out, int out_size, void* d_ws, size_t ws_size,
                              hipStream_t stream) {
  const float* x      = (const float*)d_in[0];
  const float* norm_w = (const float*)d_in[1];
  const float* norm_b = (const float*)d_in[2];
  const float* qkv_w  = (const float*)d_in[3];
  const float* qkv_b  = (const float*)d_in[4];
  const float* proj_w = (const float*)d_in[5];
  const float* proj_b = (const float*)d_in[6];
  float* out = (float*)d_out;
  char* ws = (char*)d_ws;

  u16*   wq16  = (u16*)(ws);                       // 1536*512
  u16*   wp16  = (u16*)(ws + 1572864);             // 512*512
  u16*   hT    = (u16*)(ws + 2097152);             // B*N*C
  u16*   qkT   = (u16*)(ws + 18874368);            // B*N*1024
  u16*   v     = (u16*)(ws + 52428800);            // B*C*N
  float* S     = (float*)(ws + 69206016);          // B*N*N fp32
  u16*   P     = (u16*)(ws + 136314880);           // B*N*N
  u16*   O     = (u16*)(ws + 169869312);           // B*N*C
  float* stats = (float*)(ws + 186646528);         // 256

  cvt_k<<<768, 256, 0, stream>>>(qkv_w, wq16);
  cvt_k<<<256, 256, 0, stream>>>(proj_w, wp16);
  gn_stats_k<<<Bn * Gn, 256, 0, stream>>>(x, stats);
  gn_apply_t_k<<<dim3(Nn / 64, Cn / 64, Bn), 256, 0, stream>>>(x, stats, norm_w, norm_b, hT);
  gemm_qkv_k<<<dim3(Nn / 128, 1536 / 128, Bn), 256, 0, stream>>>(wq16, hT, qkv_b, qkT, v);
  gemm_qk_k<<<dim3(Nn / 128, Nn / 128, Bn), 256, 0, stream>>>(qkT, S);
  softmax_k<<<Bn * Nn, 256, 0, stream>>>(S, P);
  gemm_pv_k<<<dim3(Cn / 128, Nn / 128, Bn), 256, 0, stream>>>(P, v, O);
  gemm_proj_k<<<dim3(Nn / 128, Cn / 128, Bn), 256, 0, stream>>>(wp16, O, proj_b, x, out);
}

// Round 4
// 254.680 us; speedup vs baseline: 4.1284x; 1.0866x over previous
//
#include <hip/hip_runtime.h>
#include <math.h>

#define Bn  16
#define Cn  512
#define Nn  1024
#define Gn  8
#define CPG 64
#define EPSf 1e-5f

typedef short           bf16x8 __attribute__((ext_vector_type(8)));
typedef float           f32x4  __attribute__((ext_vector_type(4)));
typedef unsigned short  u16;
typedef unsigned short  u16x4  __attribute__((ext_vector_type(4)));
typedef unsigned short  u16x8  __attribute__((ext_vector_type(8)));

__device__ __forceinline__ u16 f2b(float f) {
  union { float f; unsigned u; } c; c.f = f;
  unsigned r = (c.u + 0x7FFFu + ((c.u >> 16) & 1u)) >> 16;
  return (u16)r;
}

// async 16B global -> LDS DMA (dest = wave base + lane*16, no padding allowed)
__device__ __forceinline__ void g2l16(const void* g, void* l) {
  __builtin_amdgcn_global_load_lds(
      (const __attribute__((address_space(1))) unsigned int*)g,
      (__attribute__((address_space(3))) unsigned int*)l, 16, 0, 0);
}

// ---------------------------------------------------------------------------
// prep: blocks [0,768) cvt qkv_w; [768,1024) cvt proj_w; [1024,1152) gn stats
__global__ __launch_bounds__(256) void prep_k(const float* __restrict__ qkv_w,
    const float* __restrict__ proj_w, const float* __restrict__ x,
    u16* __restrict__ wq16, u16* __restrict__ wp16, float* __restrict__ stats) {
  int blk = blockIdx.x, t = threadIdx.x;
  if (blk < 1024) {
    const float* src = (blk < 768) ? qkv_w : proj_w;
    u16* dst = (blk < 768) ? wq16 : wp16;
    int i = (blk < 768 ? blk : blk - 768) * 256 + t;
    float4 v = ((const float4*)src)[i];
    u16x4 o;
    o.x = f2b(v.x); o.y = f2b(v.y); o.z = f2b(v.z); o.w = f2b(v.w);
    ((u16x4*)dst)[i] = o;
    return;
  }
  int bg = blk - 1024;
  const float4* xp = (const float4*)(x + (size_t)bg * (CPG * Nn));
  float s = 0.f, ss = 0.f;
  const int cnt4 = CPG * Nn / 4;
  for (int i = t; i < cnt4; i += 256) {
    float4 v = xp[i];
    s  += v.x + v.y + v.z + v.w;
    ss += v.x*v.x + v.y*v.y + v.z*v.z + v.w*v.w;
  }
  #pragma unroll
  for (int off = 32; off > 0; off >>= 1) {
    s  += __shfl_down(s, off);
    ss += __shfl_down(ss, off);
  }
  __shared__ float sm[4], sq[4];
  int lane = t & 63, wid = t >> 6;
  if (lane == 0) { sm[wid] = s; sq[wid] = ss; }
  __syncthreads();
  if (t == 0) {
    float S  = sm[0] + sm[1] + sm[2] + sm[3];
    float SS = sq[0] + sq[1] + sq[2] + sq[3];
    const float inv = 1.0f / (float)(CPG * Nn);
    float m = S * inv;
    float var = SS * inv - m * m;
    stats[bg]       = m;
    stats[128 + bg] = rsqrtf(var + EPSf);
  }
}

// GroupNorm apply + transpose: x[b][c][n] fp32 -> hT[b][n][c] bf16
__global__ __launch_bounds__(256) void gn_apply_t_k(const float* __restrict__ x,
    const float* __restrict__ stats, const float* __restrict__ nw,
    const float* __restrict__ nb, u16* __restrict__ hT) {
  int b = blockIdx.z, c0 = blockIdx.y * 64, n0 = blockIdx.x * 64;
  __shared__ u16 T[64][68];
  int t = threadIdx.x;
  int row = t >> 4, col4 = t & 15;
  #pragma unroll
  for (int it = 0; it < 4; it++) {
    int cc = row + it * 16;
    int c  = c0 + cc;
    int bg = b * Gn + (c >> 6);
    float mean = stats[bg], rs = stats[128 + bg];
    float a  = nw[c] * rs;
    float bb = nb[c] - mean * a;
    float4 xv = *(const float4*)&x[((size_t)(b * Cn + c)) * Nn + n0 + col4 * 4];
    u16x4 o;
    o.x = f2b(xv.x * a + bb); o.y = f2b(xv.y * a + bb);
    o.z = f2b(xv.z * a + bb); o.w = f2b(xv.w * a + bb);
    *(u16x4*)&T[cc][col4 * 4] = o;
  }
  __syncthreads();
  #pragma unroll
  for (int it = 0; it < 2; it++) {
    int ch = t + it * 256;
    int n  = ch >> 3, c8 = (ch & 7) * 8;
    u16x8 o;
    #pragma unroll
    for (int j = 0; j < 8; j++) o[j] = T[c8 + j][n];
    *(u16x8*)&hT[((size_t)(b * Nn + n0 + n)) * Cn + c0 + c8] = o;
  }
}

// ---------------------------------------------------------------------------
// GEMM core: D[128x128] = A[128xK] * B'[128xK]^T, bf16, row strides sA/sB.
// global_load_lds width-16 staging; chunk XOR swizzle keeps ds_read_b128
// conflict-free with unpadded rows.
__device__ __forceinline__ void gemm_core(const u16* __restrict__ A, size_t sA,
                                          const u16* __restrict__ B, size_t sB,
                                          int K, f32x4 acc[4][4]) {
  __shared__ u16 As[128 * 32];
  __shared__ u16 Bs[128 * 32];
  const int t = threadIdx.x;
  const int w = t >> 6, l = t & 63, quad = l >> 4, lr = l & 15;
  const int wm = (w >> 1) * 64, wn = (w & 1) * 64;

  const int ra = w * 16 + (l >> 2);
  const int p  = l & 3;
  const int q  = p ^ ((ra >> 1) & 3);
  const u16* gA0 = A + (size_t)ra * sA + q * 8;
  const u16* gA1 = A + (size_t)(ra + 64) * sA + q * 8;
  const u16* gB0 = B + (size_t)ra * sB + q * 8;
  const u16* gB1 = B + (size_t)(ra + 64) * sB + q * 8;
  u16* lA0 = As + ra * 32 + p * 8;
  u16* lA1 = As + (ra + 64) * 32 + p * 8;
  u16* lB0 = Bs + ra * 32 + p * 8;
  u16* lB1 = Bs + (ra + 64) * 32 + p * 8;

  for (int k0 = 0; k0 < K; k0 += 32) {
    __syncthreads();
    g2l16(gA0 + k0, lA0);
    g2l16(gA1 + k0, lA1);
    g2l16(gB0 + k0, lB0);
    g2l16(gB1 + k0, lB1);
    __syncthreads();
    bf16x8 af[4], bfr[4];
    #pragma unroll
    for (int fm = 0; fm < 4; fm++) {
      int r = wm + fm * 16 + lr;
      af[fm] = *(const bf16x8*)&As[r * 32 + ((quad ^ ((r >> 1) & 3)) << 3)];
    }
    #pragma unroll
    for (int fn = 0; fn < 4; fn++) {
      int r = wn + fn * 16 + lr;
      bfr[fn] = *(const bf16x8*)&Bs[r * 32 + ((quad ^ ((r >> 1) & 3)) << 3)];
    }
    #pragma unroll
    for (int fm = 0; fm < 4; fm++)
      #pragma unroll
      for (int fn = 0; fn < 4; fn++)
        acc[fm][fn] = __builtin_amdgcn_mfma_f32_16x16x32_bf16(
            af[fm], bfr[fn], acc[fm][fn], 0, 0, 0);
  }
}

#define GEMM_PRE()                                              \
  const int t = threadIdx.x;                                    \
  const int w = t >> 6, l = t & 63, quad = l >> 4, lr = l & 15; \
  const int wm = (w >> 1) * 64, wn = (w & 1) * 64;              \
  f32x4 acc[4][4];                                              \
  { f32x4 z = {0.f, 0.f, 0.f, 0.f};                             \
    for (int i = 0; i < 4; i++)                                 \
      for (int j = 0; j < 4; j++) acc[i][j] = z; }

__global__ __launch_bounds__(256) void gemm_qkv_k(const u16* __restrict__ w16,
    const u16* __restrict__ hT, const float* __restrict__ bias,
    u16* __restrict__ qkT, u16* __restrict__ v) {
  int b = blockIdx.z, m0 = blockIdx.y * 128, n0 = blockIdx.x * 128;
  GEMM_PRE();
  gemm_core(w16 + (size_t)m0 * Cn, Cn,
            hT + ((size_t)b * Nn + n0) * Cn, Cn, Cn, acc);
  #pragma unroll
  for (int fm = 0; fm < 4; fm++) {
    int mb = m0 + wm + fm * 16 + quad * 4;
    float b0 = bias[mb], b1 = bias[mb + 1], b2 = bias[mb + 2], b3 = bias[mb + 3];
    #pragma unroll
    for (int fn = 0; fn < 4; fn++) {
      int n = n0 + wn + fn * 16 + lr;
      f32x4 a = acc[fm][fn];
      if (m0 < 1024) {
        u16x4 o;
        o.x = f2b(a[0] + b0); o.y = f2b(a[1] + b1);
        o.z = f2b(a[2] + b2); o.w = f2b(a[3] + b3);
        *(u16x4*)&qkT[((size_t)(b * Nn + n)) * 1024 + mb] = o;
      } else {
        int c = mb - 1024;
        v[((size_t)(b * Cn + c    )) * Nn + n] = f2b(a[0] + b0);
        v[((size_t)(b * Cn + c + 1)) * Nn + n] = f2b(a[1] + b1);
        v[((size_t)(b * Cn + c + 2)) * Nn + n] = f2b(a[2] + b2);
        v[((size_t)(b * Cn + c + 3)) * Nn + n] = f2b(a[3] + b3);
      }
    }
  }
}

// QK^T + exp fused: P[b][i][j] = exp(scale * q_i . k_j) bf16 (unnormalized),
// rpart[b][jb][i] = partial row sums over this j-block. Softmax needs no max
// subtraction here: logits ~ N(0,1), |s| < ~10 << fp32 exp range.
__global__ __launch_bounds__(256) void gemm_qk_k(const u16* __restrict__ qkT,
    u16* __restrict__ P, float* __restrict__ rpart) {
  int b = blockIdx.z, i0 = blockIdx.y * 128, j0 = blockIdx.x * 128;
  const u16* base = qkT + (size_t)b * Nn * 1024;
  __shared__ float psum[128];
  GEMM_PRE();
  gemm_core(base + (size_t)i0 * 1024, 1024,
            base + (size_t)j0 * 1024 + 512, 1024, Cn, acc);
  if (t < 128) psum[t] = 0.f;
  __syncthreads();
  const float scale = 0.04419417382415922f;  // 512^-0.5
  #pragma unroll
  for (int fm = 0; fm < 4; fm++) {
    int ri = wm + fm * 16 + quad * 4;          // row in [0,128)
    float rs0 = 0.f, rs1 = 0.f, rs2 = 0.f, rs3 = 0.f;
    #pragma unroll
    for (int fn = 0; fn < 4; fn++) {
      int j = j0 + wn + fn * 16 + lr;
      f32x4 a = acc[fm][fn];
      float p0 = __expf(a[0] * scale);
      float p1 = __expf(a[1] * scale);
      float p2 = __expf(a[2] * scale);
      float p3 = __expf(a[3] * scale);
      u16* Pp = &P[((size_t)(b * Nn + i0 + ri)) * Nn + j];
      Pp[0]              = f2b(p0);
      Pp[Nn]             = f2b(p1);
      Pp[2 * Nn]         = f2b(p2);
      Pp[3 * (size_t)Nn] = f2b(p3);
      rs0 += p0; rs1 += p1; rs2 += p2; rs3 += p3;
    }
    #pragma unroll
    for (int mask = 1; mask < 16; mask <<= 1) {
      rs0 += __shfl_xor(rs0, mask);
      rs1 += __shfl_xor(rs1, mask);
      rs2 += __shfl_xor(rs2, mask);
      rs3 += __shfl_xor(rs3, mask);
    }
    if (lr == 0) {
      atomicAdd(&psum[ri],     rs0);
      atomicAdd(&psum[ri + 1], rs1);
      atomicAdd(&psum[ri + 2], rs2);
      atomicAdd(&psum[ri + 3], rs3);
    }
  }
  __syncthreads();
  if (t < 128)
    rpart[((size_t)(b * 8) + blockIdx.x) * Nn + i0 + t] = psum[t];
}

// PV + normalize: O[b][i][c] = (P_unnorm[i][:] . v[c][:]) / rowsum[b][i]
__global__ __launch_bounds__(256) void gemm_pv_k(const u16* __restrict__ P,
    const u16* __restrict__ v, const float* __restrict__ rpart,
    u16* __restrict__ O) {
  int b = blockIdx.z, i0 = blockIdx.y * 128, c0 = blockIdx.x * 128;
  __shared__ float rinv[128];
  {
    int t0 = threadIdx.x;
    if (t0 < 128) {
      float s = 0.f;
      #pragma unroll
      for (int jb = 0; jb < 8; jb++)
        s += rpart[((size_t)(b * 8 + jb)) * Nn + i0 + t0];
      rinv[t0] = 1.0f / s;
    }
  }
  GEMM_PRE();
  gemm_core(P + ((size_t)b * Nn + i0) * Nn, Nn,
            v + ((size_t)b * Cn + c0) * Nn, Nn, Nn, acc);
  #pragma unroll
  for (int fm = 0; fm < 4; fm++) {
    int ri = wm + fm * 16 + quad * 4;
    int ib = i0 + ri;
    #pragma unroll
    for (int fn = 0; fn < 4; fn++) {
      int c = c0 + wn + fn * 16 + lr;
      f32x4 a = acc[fm][fn];
      O[((size_t)(b * Nn + ib    )) * Cn + c] = f2b(a[0] * rinv[ri]);
      O[((size_t)(b * Nn + ib + 1)) * Cn + c] = f2b(a[1] * rinv[ri + 1]);
      O[((size_t)(b * Nn + ib + 2)) * Cn + c] = f2b(a[2] * rinv[ri + 2]);
      O[((size_t)(b * Nn + ib + 3)) * Cn + c] = f2b(a[3] * rinv[ri + 3]);
    }
  }
}

__global__ __launch_bounds__(256) void gemm_proj_k(const u16* __restrict__ pw16,
    const u16* __restrict__ O, const float* __restrict__ bias,
    const float* __restrict__ x, float* __restrict__ out) {
  int b = blockIdx.z, m0 = blockIdx.y * 128, n0 = blockIdx.x * 128;
  GEMM_PRE();
  gemm_core(pw16 + (size_t)m0 * Cn, Cn,
            O + ((size_t)b * Nn + n0) * Cn, Cn, Cn, acc);
  #pragma unroll
  for (int fm = 0; fm < 4; fm++) {
    int mb = m0 + wm + fm * 16 + quad * 4;
    #pragma unroll
    for (int fn = 0; fn < 4; fn++) {
      int n = n0 + wn + fn * 16 + lr;
      f32x4 a = acc[fm][fn];
      #pragma unroll
      for (int r = 0; r < 4; r++) {
        size_t oi = ((size_t)(b * Cn + mb + r)) * Nn + n;
        out[oi] = a[r] + bias[mb + r] + x[oi];
      }
    }
  }
}

// ---------------------------------------------------------------------------
extern "C" void kernel_launch(void* const* d_in, const int* in_sizes, int n_in,
                              void* d_out, int out_size, void* d_ws, size_t ws_size,
                              hipStream_t stream) {
  const float* x      = (const float*)d_in[0];
  const float* norm_w = (const float*)d_in[1];
  const float* norm_b = (const float*)d_in[2];
  const float* qkv_w  = (const float*)d_in[3];
  const float* qkv_b  = (const float*)d_in[4];
  const float* proj_w = (const float*)d_in[5];
  const float* proj_b = (const float*)d_in[6];
  float* out = (float*)d_out;
  char* ws = (char*)d_ws;

  u16*   wq16  = (u16*)(ws);                       // 1536*512
  u16*   wp16  = (u16*)(ws + 1572864);             // 512*512
  u16*   hT    = (u16*)(ws + 2097152);             // B*N*C bf16
  u16*   qkT   = (u16*)(ws + 35651584);            // B*N*1024 bf16
  u16*   v     = (u16*)(ws + 69206016);            // B*C*N bf16
  u16*   P     = (u16*)(ws + 85983232);            // B*N*N bf16 (unnormalized)
  u16*   O     = (u16*)(ws + 119537664);           // B*N*C bf16
  float* stats = (float*)(ws + 136314880);         // 256
  float* rpart = (float*)(ws + 136315904);         // B*8*N partial rowsums

  prep_k<<<1152, 256, 0, stream>>>(qkv_w, proj_w, x, wq16, wp16, stats);
  gn_apply_t_k<<<dim3(Nn / 64, Cn / 64, Bn), 256, 0, stream>>>(x, stats, norm_w, norm_b, hT);
  gemm_qkv_k<<<dim3(Nn / 128, 1536 / 128, Bn), 256, 0, stream>>>(wq16, hT, qkv_b, qkT, v);
  gemm_qk_k<<<dim3(Nn / 128, Nn / 128, Bn), 256, 0, stream>>>(qkT, P, rpart);
  gemm_pv_k<<<dim3(Cn / 128, Nn / 128, Bn), 256, 0, stream>>>(P, v, rpart, O);
  gemm_proj_k<<<dim3(Nn / 128, Cn / 128, Bn), 256, 0, stream>>>(wp16, O, proj_b, x, out);
}

// Round 5
// 248.108 us; speedup vs baseline: 4.2377x; 1.0265x over previous
//
#include <hip/hip_runtime.h>
#include <math.h>

#define Bn  16
#define Cn  512
#define Nn  1024
#define Gn  8
#define CPG 64
#define EPSf 1e-5f

typedef short           bf16x8 __attribute__((ext_vector_type(8)));
typedef float           f32x4  __attribute__((ext_vector_type(4)));
typedef unsigned short  u16;
typedef unsigned short  u16x4  __attribute__((ext_vector_type(4)));
typedef unsigned short  u16x8  __attribute__((ext_vector_type(8)));

__device__ __forceinline__ u16 f2b(float f) {
  union { float f; unsigned u; } c; c.f = f;
  unsigned r = (c.u + 0x7FFFu + ((c.u >> 16) & 1u)) >> 16;
  return (u16)r;
}

// async 16B global -> LDS DMA; LDS dest = wave-uniform base + lane*16
__device__ __forceinline__ void g2l16(const void* g, void* l) {
  __builtin_amdgcn_global_load_lds(
      (const __attribute__((address_space(1))) unsigned int*)g,
      (__attribute__((address_space(3))) unsigned int*)l, 16, 0, 0);
}

// ---------------------------------------------------------------------------
// prep: blocks [0,768) cvt qkv_w; [768,1024) cvt proj_w; [1024,1152) gn stats
__global__ __launch_bounds__(256) void prep_k(const float* __restrict__ qkv_w,
    const float* __restrict__ proj_w, const float* __restrict__ x,
    u16* __restrict__ wq16, u16* __restrict__ wp16, float* __restrict__ stats) {
  int blk = blockIdx.x, t = threadIdx.x;
  if (blk < 1024) {
    const float* src = (blk < 768) ? qkv_w : proj_w;
    u16* dst = (blk < 768) ? wq16 : wp16;
    int i = (blk < 768 ? blk : blk - 768) * 256 + t;
    float4 v = ((const float4*)src)[i];
    u16x4 o;
    o.x = f2b(v.x); o.y = f2b(v.y); o.z = f2b(v.z); o.w = f2b(v.w);
    ((u16x4*)dst)[i] = o;
    return;
  }
  int bg = blk - 1024;
  const float4* xp = (const float4*)(x + (size_t)bg * (CPG * Nn));
  float s = 0.f, ss = 0.f;
  const int cnt4 = CPG * Nn / 4;
  for (int i = t; i < cnt4; i += 256) {
    float4 v = xp[i];
    s  += v.x + v.y + v.z + v.w;
    ss += v.x*v.x + v.y*v.y + v.z*v.z + v.w*v.w;
  }
  #pragma unroll
  for (int off = 32; off > 0; off >>= 1) {
    s  += __shfl_down(s, off);
    ss += __shfl_down(ss, off);
  }
  __shared__ float sm[4], sq[4];
  int lane = t & 63, wid = t >> 6;
  if (lane == 0) { sm[wid] = s; sq[wid] = ss; }
  __syncthreads();
  if (t == 0) {
    float S  = sm[0] + sm[1] + sm[2] + sm[3];
    float SS = sq[0] + sq[1] + sq[2] + sq[3];
    const float inv = 1.0f / (float)(CPG * Nn);
    float m = S * inv;
    float var = SS * inv - m * m;
    stats[bg]       = m;
    stats[128 + bg] = rsqrtf(var + EPSf);
  }
}

// GroupNorm apply + transpose: x[b][c][n] fp32 -> hT[b][n][c] bf16
__global__ __launch_bounds__(256) void gn_apply_t_k(const float* __restrict__ x,
    const float* __restrict__ stats, const float* __restrict__ nw,
    const float* __restrict__ nb, u16* __restrict__ hT) {
  int b = blockIdx.z, c0 = blockIdx.y * 64, n0 = blockIdx.x * 64;
  __shared__ u16 T[64][68];
  int t = threadIdx.x;
  int row = t >> 4, col4 = t & 15;
  #pragma unroll
  for (int it = 0; it < 4; it++) {
    int cc = row + it * 16;
    int c  = c0 + cc;
    int bg = b * Gn + (c >> 6);
    float mean = stats[bg], rs = stats[128 + bg];
    float a  = nw[c] * rs;
    float bb = nb[c] - mean * a;
    float4 xv = *(const float4*)&x[((size_t)(b * Cn + c)) * Nn + n0 + col4 * 4];
    u16x4 o;
    o.x = f2b(xv.x * a + bb); o.y = f2b(xv.y * a + bb);
    o.z = f2b(xv.z * a + bb); o.w = f2b(xv.w * a + bb);
    *(u16x4*)&T[cc][col4 * 4] = o;
  }
  __syncthreads();
  #pragma unroll
  for (int it = 0; it < 2; it++) {
    int ch = t + it * 256;
    int n  = ch >> 3, c8 = (ch & 7) * 8;
    u16x8 o;
    #pragma unroll
    for (int j = 0; j < 8; j++) o[j] = T[c8 + j][n];
    *(u16x8*)&hT[((size_t)(b * Nn + n0 + n)) * Cn + c0 + c8] = o;
  }
}

// ---------------------------------------------------------------------------
// GEMM core, BK=64: D[128x128] = A[128xK] * B'[128xK]^T, bf16.
// global_load_lds: per call c, wave w, lane l -> LDS slot (c*4+w)*64+l
// (row r = c*32+w*8+(l>>3), stored chunk p = l&7); lane loads global chunk
// g = (l&7)^(l>>3)  ==  p ^ (r&7).  Reader: stored chunk (s*4+quad)^(lr&7)
// -> 2-way max bank aliasing (free).
__device__ __forceinline__ void gemm_core(const u16* __restrict__ A, size_t sA,
                                          const u16* __restrict__ B, size_t sB,
                                          int K, f32x4 acc[4][4]) {
  __shared__ u16 As[128 * 64];
  __shared__ u16 Bs[128 * 64];
  const int t = threadIdx.x;
  const int w = t >> 6, l = t & 63, quad = l >> 4, lr = l & 15;
  const int wm = (w >> 1) * 64, wn = (w & 1) * 64;

  const int g = ((l & 7) ^ (l >> 3)) * 8;   // global chunk offset (u16 units)
  const int r_l = l >> 3;                   // lane's row-within-8

  for (int k0 = 0; k0 < K; k0 += 64) {
    __syncthreads();
    #pragma unroll
    for (int c = 0; c < 4; c++) {
      int r = c * 32 + w * 8 + r_l;
      g2l16(A + (size_t)r * sA + k0 + g, As + (size_t)(c * 4 + w) * 512);
      g2l16(B + (size_t)r * sB + k0 + g, Bs + (size_t)(c * 4 + w) * 512);
    }
    __syncthreads();
    #pragma unroll
    for (int s = 0; s < 2; s++) {
      bf16x8 af[4], bfr[4];
      #pragma unroll
      for (int fm = 0; fm < 4; fm++) {
        int r = wm + fm * 16 + lr;
        af[fm] = *(const bf16x8*)&As[r * 64 + (((s * 4 + quad) ^ (lr & 7)) << 3)];
      }
      #pragma unroll
      for (int fn = 0; fn < 4; fn++) {
        int r = wn + fn * 16 + lr;
        bfr[fn] = *(const bf16x8*)&Bs[r * 64 + (((s * 4 + quad) ^ (lr & 7)) << 3)];
      }
      #pragma unroll
      for (int fm = 0; fm < 4; fm++)
        #pragma unroll
        for (int fn = 0; fn < 4; fn++)
          acc[fm][fn] = __builtin_amdgcn_mfma_f32_16x16x32_bf16(
              af[fm], bfr[fn], acc[fm][fn], 0, 0, 0);
    }
  }
}

#define GEMM_PRE()                                              \
  const int t = threadIdx.x;                                    \
  const int w = t >> 6, l = t & 63, quad = l >> 4, lr = l & 15; \
  const int wm = (w >> 1) * 64, wn = (w & 1) * 64;              \
  f32x4 acc[4][4];                                              \
  { f32x4 z = {0.f, 0.f, 0.f, 0.f};                             \
    for (int i = 0; i < 4; i++)                                 \
      for (int j = 0; j < 4; j++) acc[i][j] = z; }

__global__ __launch_bounds__(256) void gemm_qkv_k(const u16* __restrict__ w16,
    const u16* __restrict__ hT, const float* __restrict__ bias,
    u16* __restrict__ qkT, u16* __restrict__ v) {
  int b = blockIdx.z, m0 = blockIdx.y * 128, n0 = blockIdx.x * 128;
  GEMM_PRE();
  gemm_core(w16 + (size_t)m0 * Cn, Cn,
            hT + ((size_t)b * Nn + n0) * Cn, Cn, Cn, acc);
  #pragma unroll
  for (int fm = 0; fm < 4; fm++) {
    int mb = m0 + wm + fm * 16 + quad * 4;
    float b0 = bias[mb], b1 = bias[mb + 1], b2 = bias[mb + 2], b3 = bias[mb + 3];
    #pragma unroll
    for (int fn = 0; fn < 4; fn++) {
      int n = n0 + wn + fn * 16 + lr;
      f32x4 a = acc[fm][fn];
      if (m0 < 1024) {
        u16x4 o;
        o.x = f2b(a[0] + b0); o.y = f2b(a[1] + b1);
        o.z = f2b(a[2] + b2); o.w = f2b(a[3] + b3);
        *(u16x4*)&qkT[((size_t)(b * Nn + n)) * 1024 + mb] = o;
      } else {
        int c = mb - 1024;
        v[((size_t)(b * Cn + c    )) * Nn + n] = f2b(a[0] + b0);
        v[((size_t)(b * Cn + c + 1)) * Nn + n] = f2b(a[1] + b1);
        v[((size_t)(b * Cn + c + 2)) * Nn + n] = f2b(a[2] + b2);
        v[((size_t)(b * Cn + c + 3)) * Nn + n] = f2b(a[3] + b3);
      }
    }
  }
}

// QK^T + exp fused: P = exp(scale*q.k) bf16 unnormalized; rpart = partial row
// sums per j-block. No max subtraction needed: logits ~ N(0,1).
__global__ __launch_bounds__(256) void gemm_qk_k(const u16* __restrict__ qkT,
    u16* __restrict__ P, float* __restrict__ rpart) {
  int b = blockIdx.z, i0 = blockIdx.y * 128, j0 = blockIdx.x * 128;
  const u16* base = qkT + (size_t)b * Nn * 1024;
  __shared__ float psum[128];
  GEMM_PRE();
  gemm_core(base + (size_t)i0 * 1024, 1024,
            base + (size_t)j0 * 1024 + 512, 1024, Cn, acc);
  if (t < 128) psum[t] = 0.f;
  __syncthreads();
  const float scale = 0.04419417382415922f;  // 512^-0.5
  #pragma unroll
  for (int fm = 0; fm < 4; fm++) {
    int ri = wm + fm * 16 + quad * 4;
    float rs0 = 0.f, rs1 = 0.f, rs2 = 0.f, rs3 = 0.f;
    #pragma unroll
    for (int fn = 0; fn < 4; fn++) {
      int j = j0 + wn + fn * 16 + lr;
      f32x4 a = acc[fm][fn];
      float p0 = __expf(a[0] * scale);
      float p1 = __expf(a[1] * scale);
      float p2 = __expf(a[2] * scale);
      float p3 = __expf(a[3] * scale);
      u16* Pp = &P[((size_t)(b * Nn + i0 + ri)) * Nn + j];
      Pp[0]              = f2b(p0);
      Pp[Nn]             = f2b(p1);
      Pp[2 * Nn]         = f2b(p2);
      Pp[3 * (size_t)Nn] = f2b(p3);
      rs0 += p0; rs1 += p1; rs2 += p2; rs3 += p3;
    }
    #pragma unroll
    for (int mask = 1; mask < 16; mask <<= 1) {
      rs0 += __shfl_xor(rs0, mask);
      rs1 += __shfl_xor(rs1, mask);
      rs2 += __shfl_xor(rs2, mask);
      rs3 += __shfl_xor(rs3, mask);
    }
    if (lr == 0) {
      atomicAdd(&psum[ri],     rs0);
      atomicAdd(&psum[ri + 1], rs1);
      atomicAdd(&psum[ri + 2], rs2);
      atomicAdd(&psum[ri + 3], rs3);
    }
  }
  __syncthreads();
  if (t < 128)
    rpart[((size_t)(b * 8) + blockIdx.x) * Nn + i0 + t] = psum[t];
}

// PV + normalize: O[b][i][c] = (P_unnorm[i][:] . v[c][:]) / rowsum[b][i]
__global__ __launch_bounds__(256) void gemm_pv_k(const u16* __restrict__ P,
    const u16* __restrict__ v, const float* __restrict__ rpart,
    u16* __restrict__ O) {
  int b = blockIdx.z, i0 = blockIdx.y * 128, c0 = blockIdx.x * 128;
  __shared__ float rinv[128];
  {
    int t0 = threadIdx.x;
    if (t0 < 128) {
      float s = 0.f;
      #pragma unroll
      for (int jb = 0; jb < 8; jb++)
        s += rpart[((size_t)(b * 8 + jb)) * Nn + i0 + t0];
      rinv[t0] = 1.0f / s;
    }
  }
  GEMM_PRE();
  gemm_core(P + ((size_t)b * Nn + i0) * Nn, Nn,
            v + ((size_t)b * Cn + c0) * Nn, Nn, Nn, acc);
  #pragma unroll
  for (int fm = 0; fm < 4; fm++) {
    int ri = wm + fm * 16 + quad * 4;
    int ib = i0 + ri;
    #pragma unroll
    for (int fn = 0; fn < 4; fn++) {
      int c = c0 + wn + fn * 16 + lr;
      f32x4 a = acc[fm][fn];
      O[((size_t)(b * Nn + ib    )) * Cn + c] = f2b(a[0] * rinv[ri]);
      O[((size_t)(b * Nn + ib + 1)) * Cn + c] = f2b(a[1] * rinv[ri + 1]);
      O[((size_t)(b * Nn + ib + 2)) * Cn + c] = f2b(a[2] * rinv[ri + 2]);
      O[((size_t)(b * Nn + ib + 3)) * Cn + c] = f2b(a[3] * rinv[ri + 3]);
    }
  }
}

__global__ __launch_bounds__(256) void gemm_proj_k(const u16* __restrict__ pw16,
    const u16* __restrict__ O, const float* __restrict__ bias,
    const float* __restrict__ x, float* __restrict__ out) {
  int b = blockIdx.z, m0 = blockIdx.y * 128, n0 = blockIdx.x * 128;
  GEMM_PRE();
  gemm_core(pw16 + (size_t)m0 * Cn, Cn,
            O + ((size_t)b * Nn + n0) * Cn, Cn, Cn, acc);
  #pragma unroll
  for (int fm = 0; fm < 4; fm++) {
    int mb = m0 + wm + fm * 16 + quad * 4;
    #pragma unroll
    for (int fn = 0; fn < 4; fn++) {
      int n = n0 + wn + fn * 16 + lr;
      f32x4 a = acc[fm][fn];
      #pragma unroll
      for (int r = 0; r < 4; r++) {
        size_t oi = ((size_t)(b * Cn + mb + r)) * Nn + n;
        out[oi] = a[r] + bias[mb + r] + x[oi];
      }
    }
  }
}

// ---------------------------------------------------------------------------
extern "C" void kernel_launch(void* const* d_in, const int* in_sizes, int n_in,
                              void* d_out, int out_size, void* d_ws, size_t ws_size,
                              hipStream_t stream) {
  const float* x      = (const float*)d_in[0];
  const float* norm_w = (const float*)d_in[1];
  const float* norm_b = (const float*)d_in[2];
  const float* qkv_w  = (const float*)d_in[3];
  const float* qkv_b  = (const float*)d_in[4];
  const float* proj_w = (const float*)d_in[5];
  const float* proj_b = (const float*)d_in[6];
  float* out = (float*)d_out;
  char* ws = (char*)d_ws;

  u16*   wq16  = (u16*)(ws);                       // 1536*512
  u16*   wp16  = (u16*)(ws + 1572864);             // 512*512
  u16*   hT    = (u16*)(ws + 2097152);             // B*N*C bf16
  u16*   qkT   = (u16*)(ws + 35651584);            // B*N*1024 bf16
  u16*   v     = (u16*)(ws + 69206016);            // B*C*N bf16
  u16*   P     = (u16*)(ws + 85983232);            // B*N*N bf16 (unnormalized)
  u16*   O     = (u16*)(ws + 119537664);           // B*N*C bf16
  float* stats = (float*)(ws + 136314880);         // 256
  float* rpart = (float*)(ws + 136315904);         // B*8*N partial rowsums

  prep_k<<<1152, 256, 0, stream>>>(qkv_w, proj_w, x, wq16, wp16, stats);
  gn_apply_t_k<<<dim3(Nn / 64, Cn / 64, Bn), 256, 0, stream>>>(x, stats, norm_w, norm_b, hT);
  gemm_qkv_k<<<dim3(Nn / 128, 1536 / 128, Bn), 256, 0, stream>>>(wq16, hT, qkv_b, qkT, v);
  gemm_qk_k<<<dim3(Nn / 128, Nn / 128, Bn), 256, 0, stream>>>(qkT, P, rpart);
  gemm_pv_k<<<dim3(Cn / 128, Nn / 128, Bn), 256, 0, stream>>>(P, v, rpart, O);
  gemm_proj_k<<<dim3(Nn / 128, Cn / 128, Bn), 256, 0, stream>>>(wp16, O, proj_b, x, out);
}

// Round 7
// 242.505 us; speedup vs baseline: 4.3356x; 1.0231x over previous
//
#include <hip/hip_runtime.h>
#include <math.h>

#define Bn   16
#define Cn   512
#define Nn   1024
#define Gn   8
#define CPG  64
#define EPSf 1e-5f

typedef short           bf16x8 __attribute__((ext_vector_type(8)));
typedef float           f32x4  __attribute__((ext_vector_type(4)));
typedef unsigned short  u16;
typedef unsigned short  u16x4  __attribute__((ext_vector_type(4)));
typedef unsigned short  u16x8  __attribute__((ext_vector_type(8)));

__device__ __forceinline__ u16 f2b(float f) {
  union { float f; unsigned u; } c; c.f = f;
  unsigned r = (c.u + 0x7FFFu + ((c.u >> 16) & 1u)) >> 16;
  return (u16)r;
}

// async 16B global -> LDS DMA; LDS dest = wave-uniform base + lane*16
__device__ __forceinline__ void g2l16(const void* g, void* l) {
  __builtin_amdgcn_global_load_lds(
      (const __attribute__((address_space(1))) unsigned int*)g,
      (__attribute__((address_space(3))) unsigned int*)l, 16, 0, 0);
}

// GEMM core (BK=32, round-4 proven): D[128x128] = A[128xK]*B'[128xK]^T bf16.
// LDS unpadded 32-elem rows, chunk-XOR swizzle -> conflict-free ds_read_b128.
__device__ __forceinline__ void gemm_core(u16* As, u16* Bs,
    const u16* __restrict__ A, size_t sA,
    const u16* __restrict__ B, size_t sB, int K, f32x4 acc[4][4]) {
  const int t = threadIdx.x;
  const int w = t >> 6, l = t & 63, quad = l >> 4, lr = l & 15;
  const int wm = (w >> 1) * 64, wn = (w & 1) * 64;

  const int ra = w * 16 + (l >> 2);
  const int p  = l & 3;
  const int q  = p ^ ((ra >> 1) & 3);
  const u16* gA0 = A + (size_t)ra * sA + q * 8;
  const u16* gA1 = A + (size_t)(ra + 64) * sA + q * 8;
  const u16* gB0 = B + (size_t)ra * sB + q * 8;
  const u16* gB1 = B + (size_t)(ra + 64) * sB + q * 8;
  u16* lA0 = As + ra * 32 + p * 8;
  u16* lA1 = As + (ra + 64) * 32 + p * 8;
  u16* lB0 = Bs + ra * 32 + p * 8;
  u16* lB1 = Bs + (ra + 64) * 32 + p * 8;

  for (int k0 = 0; k0 < K; k0 += 32) {
    __syncthreads();
    g2l16(gA0 + k0, lA0);
    g2l16(gA1 + k0, lA1);
    g2l16(gB0 + k0, lB0);
    g2l16(gB1 + k0, lB1);
    __syncthreads();
    bf16x8 af[4], bfr[4];
    #pragma unroll
    for (int fm = 0; fm < 4; fm++) {
      int r = wm + fm * 16 + lr;
      af[fm] = *(const bf16x8*)&As[r * 32 + ((quad ^ ((r >> 1) & 3)) << 3)];
    }
    #pragma unroll
    for (int fn = 0; fn < 4; fn++) {
      int r = wn + fn * 16 + lr;
      bfr[fn] = *(const bf16x8*)&Bs[r * 32 + ((quad ^ ((r >> 1) & 3)) << 3)];
    }
    #pragma unroll
    for (int fm = 0; fm < 4; fm++)
      #pragma unroll
      for (int fn = 0; fn < 4; fn++)
        acc[fm][fn] = __builtin_amdgcn_mfma_f32_16x16x32_bf16(
            af[fm], bfr[fn], acc[fm][fn], 0, 0, 0);
  }
}

#define GEMM_PRE()                                              \
  const int t = threadIdx.x;                                    \
  const int w = t >> 6, l = t & 63, quad = l >> 4, lr = l & 15; \
  const int wm = (w >> 1) * 64, wn = (w & 1) * 64;              \
  (void)w; (void)wm; (void)wn;                                  \
  f32x4 acc[4][4];                                              \
  { f32x4 z = {0.f, 0.f, 0.f, 0.f};                             \
    for (int i_ = 0; i_ < 4; i_++)                              \
      for (int j_ = 0; j_ < 4; j_++) acc[i_][j_] = z; }

// ---------------------------------------------------------------------------
// prep: [0,512) qk-weight cvt | [512,576) WvT transpose-cvt | [576,578) bias2
//       | [578,706) gn stats | [706,962) proj_w cvt
__global__ __launch_bounds__(256) void prep_k(const float* __restrict__ qkv_w,
    const float* __restrict__ proj_w, const float* __restrict__ qkv_b,
    const float* __restrict__ x, u16* __restrict__ wqk16,
    u16* __restrict__ wvT16, u16* __restrict__ pw16,
    float* __restrict__ bias2, float* __restrict__ stats) {
  __shared__ u16 T[64][68];
  __shared__ float sm[4], sq[4];
  int bid = blockIdx.x, t = threadIdx.x;
  if (bid < 512) {                       // q,k weights: 131072 float4 exact
    int i = bid * 256 + t;
    float4 v = ((const float4*)qkv_w)[i];
    u16x4 o;
    o.x = f2b(v.x); o.y = f2b(v.y); o.z = f2b(v.z); o.w = f2b(v.w);
    ((u16x4*)wqk16)[i] = o;
  } else if (bid < 576) {                // WvT[d][c] = Wv[c][d] bf16
    int tile = bid - 512, tx = tile & 7, ty = tile >> 3;
    int row = t >> 4, col4 = t & 15;
    #pragma unroll
    for (int it = 0; it < 4; it++) {
      int cc = row + it * 16;
      float4 v = *(const float4*)&qkv_w[(size_t)(1024 + ty * 64 + cc) * 512 + tx * 64 + col4 * 4];
      u16x4 o;
      o.x = f2b(v.x); o.y = f2b(v.y); o.z = f2b(v.z); o.w = f2b(v.w);
      *(u16x4*)&T[cc][col4 * 4] = o;
    }
    __syncthreads();
    #pragma unroll
    for (int it = 0; it < 2; it++) {
      int ch = t + it * 256;
      int d = ch >> 3, c8 = (ch & 7) * 8;
      u16x8 o;
      #pragma unroll
      for (int j = 0; j < 8; j++) o[j] = T[c8 + j][d];
      *(u16x8*)&wvT16[(size_t)(tx * 64 + d) * 512 + ty * 64 + c8] = o;
    }
  } else if (bid < 578) {                // bias2 = proj_w @ v_bias (fp32)
    int m = (bid - 576) * 256 + t;
    float s = 0.f;
    for (int c = 0; c < 512; c++)
      s += proj_w[(size_t)m * 512 + c] * qkv_b[1024 + c];
    bias2[m] = s;
  } else if (bid < 706) {                // gn stats: one (b,group) per block
    int bg = bid - 578;
    const float4* xp = (const float4*)(x + (size_t)bg * (CPG * Nn));
    float s = 0.f, ss = 0.f;
    const int cnt4 = CPG * Nn / 4;
    for (int i = t; i < cnt4; i += 256) {
      float4 v = xp[i];
      s  += v.x + v.y + v.z + v.w;
      ss += v.x * v.x + v.y * v.y + v.z * v.z + v.w * v.w;
    }
    #pragma unroll
    for (int off = 32; off > 0; off >>= 1) {
      s  += __shfl_down(s, off);
      ss += __shfl_down(ss, off);
    }
    int lane = t & 63, wid = t >> 6;
    if (lane == 0) { sm[wid] = s; sq[wid] = ss; }
    __syncthreads();
    if (t == 0) {
      float S  = sm[0] + sm[1] + sm[2] + sm[3];
      float SS = sq[0] + sq[1] + sq[2] + sq[3];
      const float inv = 1.0f / (float)(CPG * Nn);
      float m = S * inv;
      float var = SS * inv - m * m;
      stats[bg]       = m;
      stats[128 + bg] = rsqrtf(var + EPSf);
    }
  } else {                               // proj_w cvt: 65536 float4
    int i = (bid - 706) * 256 + t;
    float4 v = ((const float4*)proj_w)[i];
    u16x4 o;
    o.x = f2b(v.x); o.y = f2b(v.y); o.z = f2b(v.z); o.w = f2b(v.w);
    ((u16x4*)pw16)[i] = o;
  }
}

// ---------------------------------------------------------------------------
// gnw2: [0,16) W2 = pw16 @ Wv (via wvT16) | [16,2064) groupnorm apply+transpose
__global__ __launch_bounds__(256) void gnw2_k(const float* __restrict__ x,
    const float* __restrict__ stats, const float* __restrict__ nw,
    const float* __restrict__ nb, const u16* __restrict__ pw16,
    const u16* __restrict__ wvT16, u16* __restrict__ W2, u16* __restrict__ hT) {
  __shared__ u16 AsBs[8192];
  int bid = blockIdx.x;
  if (bid < 16) {
    int m0 = (bid >> 2) * 128, d0 = (bid & 3) * 128;
    GEMM_PRE();
    gemm_core(AsBs, AsBs + 4096, pw16 + (size_t)m0 * 512, 512,
              wvT16 + (size_t)d0 * 512, 512, 512, acc);
    #pragma unroll
    for (int fm = 0; fm < 4; fm++) {
      int m = m0 + wm + fm * 16 + quad * 4;
      #pragma unroll
      for (int fn = 0; fn < 4; fn++) {
        int d = d0 + wn + fn * 16 + lr;
        f32x4 a = acc[fm][fn];
        W2[(size_t)(m    ) * 512 + d] = f2b(a[0]);
        W2[(size_t)(m + 1) * 512 + d] = f2b(a[1]);
        W2[(size_t)(m + 2) * 512 + d] = f2b(a[2]);
        W2[(size_t)(m + 3) * 512 + d] = f2b(a[3]);
      }
    }
    return;
  }
  int u = bid - 16;                      // 2048 tiles: 64c x 64n
  int b = u >> 7, rem = u & 127, c0 = (rem >> 4) * 64, n0 = (rem & 15) * 64;
  u16 (*T)[68] = (u16(*)[68])AsBs;
  int t = threadIdx.x;
  int row = t >> 4, col4 = t & 15;
  #pragma unroll
  for (int it = 0; it < 4; it++) {
    int cc = row + it * 16;
    int c  = c0 + cc;
    int bg = b * Gn + (c >> 6);
    float mean = stats[bg], rstd = stats[128 + bg];
    float a  = nw[c] * rstd;
    float bb = nb[c] - mean * a;
    float4 xv = *(const float4*)&x[((size_t)(b * Cn + c)) * Nn + n0 + col4 * 4];
    u16x4 o;
    o.x = f2b(xv.x * a + bb); o.y = f2b(xv.y * a + bb);
    o.z = f2b(xv.z * a + bb); o.w = f2b(xv.w * a + bb);
    *(u16x4*)&T[cc][col4 * 4] = o;
  }
  __syncthreads();
  #pragma unroll
  for (int it = 0; it < 2; it++) {
    int ch = t + it * 256;
    int n  = ch >> 3, c8 = (ch & 7) * 8;
    u16x8 o;
    #pragma unroll
    for (int j = 0; j < 8; j++) o[j] = T[c8 + j][n];
    *(u16x8*)&hT[((size_t)(b * Nn + n0 + n)) * 512 + c0 + c8] = o;
  }
}

// ---------------------------------------------------------------------------
// qkvp: [0,1024) qkT[b][n][m] = wqk.h + bias  |  [1024,1536) VP = W2 @ h
__global__ __launch_bounds__(256) void qkvp_k(const u16* __restrict__ wqk16,
    const u16* __restrict__ W2, const u16* __restrict__ hT,
    const float* __restrict__ qkv_b, u16* __restrict__ qkT,
    u16* __restrict__ VP) {
  __shared__ u16 AsBs[8192];
  int u = blockIdx.x;
  GEMM_PRE();
  if (u < 1024) {
    int b = u >> 6, rem = u & 63, m0 = (rem >> 3) * 128, n0 = (rem & 7) * 128;
    gemm_core(AsBs, AsBs + 4096, wqk16 + (size_t)m0 * 512, 512,
              hT + ((size_t)(b * Nn + n0)) * 512, 512, 512, acc);
    #pragma unroll
    for (int fm = 0; fm < 4; fm++) {
      int mb = m0 + wm + fm * 16 + quad * 4;
      float b0 = qkv_b[mb], b1 = qkv_b[mb + 1], b2 = qkv_b[mb + 2], b3 = qkv_b[mb + 3];
      #pragma unroll
      for (int fn = 0; fn < 4; fn++) {
        int n = n0 + wn + fn * 16 + lr;
        f32x4 a = acc[fm][fn];
        u16x4 o;
        o.x = f2b(a[0] + b0); o.y = f2b(a[1] + b1);
        o.z = f2b(a[2] + b2); o.w = f2b(a[3] + b3);
        *(u16x4*)&qkT[((size_t)(b * Nn + n)) * 1024 + mb] = o;
      }
    }
  } else {
    int u2 = u - 1024;
    int b = u2 >> 5, rem = u2 & 31, m0 = (rem >> 3) * 128, j0 = (rem & 7) * 128;
    gemm_core(AsBs, AsBs + 4096, W2 + (size_t)m0 * 512, 512,
              hT + ((size_t)(b * Nn + j0)) * 512, 512, 512, acc);
    #pragma unroll
    for (int fm = 0; fm < 4; fm++) {
      int m = m0 + wm + fm * 16 + quad * 4;
      #pragma unroll
      for (int fn = 0; fn < 4; fn++) {
        int j = j0 + wn + fn * 16 + lr;
        f32x4 a = acc[fm][fn];
        VP[((size_t)(b * 512 + m    )) * 1024 + j] = f2b(a[0]);
        VP[((size_t)(b * 512 + m + 1)) * 1024 + j] = f2b(a[1]);
        VP[((size_t)(b * 512 + m + 2)) * 1024 + j] = f2b(a[2]);
        VP[((size_t)(b * 512 + m + 3)) * 1024 + j] = f2b(a[3]);
      }
    }
  }
}

// ---------------------------------------------------------------------------
// qkexp: Pm = exp(scale*q.k) bf16 unnormalized; rpart partial row sums.
// No max subtraction: logits ~ N(0,1).
__global__ __launch_bounds__(256) void qkexp_k(const u16* __restrict__ qkT,
    u16* __restrict__ Pm, float* __restrict__ rpart) {
  __shared__ u16 AsBs[8192];
  __shared__ float psum[128];
  int u = blockIdx.x;
  int b = u >> 6, rem = u & 63, i0 = (rem >> 3) * 128, j0 = (rem & 7) * 128;
  const u16* base = qkT + (size_t)b * Nn * 1024;
  GEMM_PRE();
  gemm_core(AsBs, AsBs + 4096, base + (size_t)i0 * 1024, 1024,
            base + (size_t)j0 * 1024 + 512, 1024, 512, acc);
  if (t < 128) psum[t] = 0.f;
  __syncthreads();
  const float scale = 0.04419417382415922f;  // 512^-0.5
  #pragma unroll
  for (int fm = 0; fm < 4; fm++) {
    int ri = wm + fm * 16 + quad * 4;
    float rs0 = 0.f, rs1 = 0.f, rs2 = 0.f, rs3 = 0.f;
    #pragma unroll
    for (int fn = 0; fn < 4; fn++) {
      int j = j0 + wn + fn * 16 + lr;
      f32x4 a = acc[fm][fn];
      float p0 = __expf(a[0] * scale);
      float p1 = __expf(a[1] * scale);
      float p2 = __expf(a[2] * scale);
      float p3 = __expf(a[3] * scale);
      u16* Pp = &Pm[((size_t)(b * Nn + i0 + ri)) * 1024 + j];
      Pp[0]    = f2b(p0);
      Pp[1024] = f2b(p1);
      Pp[2048] = f2b(p2);
      Pp[3072] = f2b(p3);
      rs0 += p0; rs1 += p1; rs2 += p2; rs3 += p3;
    }
    #pragma unroll
    for (int mask = 1; mask < 16; mask <<= 1) {
      rs0 += __shfl_xor(rs0, mask);
      rs1 += __shfl_xor(rs1, mask);
      rs2 += __shfl_xor(rs2, mask);
      rs3 += __shfl_xor(rs3, mask);
    }
    if (lr == 0) {
      atomicAdd(&psum[ri],     rs0);
      atomicAdd(&psum[ri + 1], rs1);
      atomicAdd(&psum[ri + 2], rs2);
      atomicAdd(&psum[ri + 3], rs3);
    }
  }
  __syncthreads();
  if (t < 128)
    rpart[((size_t)(b * 8) + (rem & 7)) * 1024 + i0 + t] = psum[t];
}

// ---------------------------------------------------------------------------
// pvout: out = (VP @ Pm^T)/r + bias2 + proj_b + x
__global__ __launch_bounds__(256) void pvout_k(const u16* __restrict__ VP,
    const u16* __restrict__ Pm, const float* __restrict__ rpart,
    const float* __restrict__ bias2, const float* __restrict__ proj_b,
    const float* __restrict__ x, float* __restrict__ out) {
  __shared__ u16 AsBs[8192];
  __shared__ float rinv[128];
  int bid = blockIdx.x;
  int b = bid >> 5, rem = bid & 31, m0 = (rem >> 3) * 128, i0 = (rem & 7) * 128;
  if (threadIdx.x < 128) {
    float s = 0.f;
    #pragma unroll
    for (int jb = 0; jb < 8; jb++)
      s += rpart[((size_t)(b * 8 + jb)) * 1024 + i0 + threadIdx.x];
    rinv[threadIdx.x] = 1.0f / s;
  }
  GEMM_PRE();
  gemm_core(AsBs, AsBs + 4096, VP + ((size_t)(b * 512 + m0)) * 1024, 1024,
            Pm + ((size_t)(b * Nn + i0)) * 1024, 1024, 1024, acc);
  #pragma unroll
  for (int fm = 0; fm < 4; fm++) {
    int m = m0 + wm + fm * 16 + quad * 4;
    float c0 = bias2[m    ] + proj_b[m    ];
    float c1 = bias2[m + 1] + proj_b[m + 1];
    float c2 = bias2[m + 2] + proj_b[m + 2];
    float c3 = bias2[m + 3] + proj_b[m + 3];
    #pragma unroll
    for (int fn = 0; fn < 4; fn++) {
      int il = wn + fn * 16 + lr;
      int i  = i0 + il;
      float ri = rinv[il];
      f32x4 a = acc[fm][fn];
      size_t o0 = ((size_t)(b * Cn + m)) * Nn + i;
      out[o0                  ] = a[0] * ri + c0 + x[o0                  ];
      out[o0 + Nn             ] = a[1] * ri + c1 + x[o0 + Nn             ];
      out[o0 + 2 * Nn         ] = a[2] * ri + c2 + x[o0 + 2 * Nn         ];
      out[o0 + 3 * (size_t)Nn] = a[3] * ri + c3 + x[o0 + 3 * (size_t)Nn];
    }
  }
}

// ---------------------------------------------------------------------------
extern "C" void kernel_launch(void* const* d_in, const int* in_sizes, int n_in,
                              void* d_out, int out_size, void* d_ws, size_t ws_size,
                              hipStream_t stream) {
  const float* x      = (const float*)d_in[0];
  const float* norm_w = (const float*)d_in[1];
  const float* norm_b = (const float*)d_in[2];
  const float* qkv_w  = (const float*)d_in[3];
  const float* qkv_b  = (const float*)d_in[4];
  const float* proj_w = (const float*)d_in[5];
  const float* proj_b = (const float*)d_in[6];
  float* out = (float*)d_out;
  char* ws = (char*)d_ws;

  u16*   wqk16 = (u16*)(ws);                     // 1024x512
  u16*   wvT16 = (u16*)(ws + 1048576);           // 512x512 (Wv^T)
  u16*   pw16  = (u16*)(ws + 1572864);           // 512x512
  u16*   W2    = (u16*)(ws + 2097152);           // 512x512 (= proj_w @ Wv)
  float* bias2 = (float*)(ws + 2621440);         // 512
  float* stats = (float*)(ws + 2623488);         // 256 (mean|rstd)
  u16*   hT    = (u16*)(ws + 2624512);           // B*N*C
  u16*   qkT   = (u16*)(ws + 19401728);          // B*N*1024
  u16*   VP    = (u16*)(ws + 52956160);          // B*512*N
  u16*   Pm    = (u16*)(ws + 69733376);          // B*N*N
  float* rpart = (float*)(ws + 103287808);       // B*8*N

  prep_k<<<962, 256, 0, stream>>>(qkv_w, proj_w, qkv_b, x, wqk16, wvT16, pw16, bias2, stats);
  gnw2_k<<<2064, 256, 0, stream>>>(x, stats, norm_w, norm_b, pw16, wvT16, W2, hT);
  qkvp_k<<<1536, 256, 0, stream>>>(wqk16, W2, hT, qkv_b, qkT, VP);
  qkexp_k<<<1024, 256, 0, stream>>>(qkT, Pm, rpart);
  pvout_k<<<512, 256, 0, stream>>>(VP, Pm, rpart, bias2, proj_b, x, out);
}

// Round 8
// 241.973 us; speedup vs baseline: 4.3452x; 1.0022x over previous
//
#include <hip/hip_runtime.h>
#include <hip/hip_cooperative_groups.h>
#include <math.h>

namespace cg = cooperative_groups;

#define Bn    16
#define Cn    512
#define Nn    1024
#define Gn    8
#define CPG   64
#define EPSf  1e-5f
#define GRIDC 512

typedef short           bf16x8 __attribute__((ext_vector_type(8)));
typedef float           f32x4  __attribute__((ext_vector_type(4)));
typedef unsigned short  u16;
typedef unsigned short  u16x4  __attribute__((ext_vector_type(4)));
typedef unsigned short  u16x8  __attribute__((ext_vector_type(8)));

__device__ __forceinline__ u16 f2b(float f) {
  union { float f; unsigned u; } c; c.f = f;
  unsigned r = (c.u + 0x7FFFu + ((c.u >> 16) & 1u)) >> 16;
  return (u16)r;
}

// async 16B global -> LDS DMA; LDS dest = wave-uniform base + lane*16
__device__ __forceinline__ void g2l16(const void* g, void* l) {
  __builtin_amdgcn_global_load_lds(
      (const __attribute__((address_space(1))) unsigned int*)g,
      (__attribute__((address_space(3))) unsigned int*)l, 16, 0, 0);
}

// GEMM core (BK=32, proven): D[128x128] = A[128xK]*B'[128xK]^T bf16.
// LDS unpadded 32-elem rows, chunk-XOR swizzle -> conflict-free ds_read_b128.
__device__ __forceinline__ void gemm_core(u16* As, u16* Bs,
    const u16* __restrict__ A, size_t sA,
    const u16* __restrict__ B, size_t sB, int K, f32x4 acc[4][4]) {
  const int t = threadIdx.x;
  const int w = t >> 6, l = t & 63, quad = l >> 4, lr = l & 15;
  const int wm = (w >> 1) * 64, wn = (w & 1) * 64;

  const int ra = w * 16 + (l >> 2);
  const int p  = l & 3;
  const int q  = p ^ ((ra >> 1) & 3);
  const u16* gA0 = A + (size_t)ra * sA + q * 8;
  const u16* gA1 = A + (size_t)(ra + 64) * sA + q * 8;
  const u16* gB0 = B + (size_t)ra * sB + q * 8;
  const u16* gB1 = B + (size_t)(ra + 64) * sB + q * 8;
  u16* lA0 = As + ra * 32 + p * 8;
  u16* lA1 = As + (ra + 64) * 32 + p * 8;
  u16* lB0 = Bs + ra * 32 + p * 8;
  u16* lB1 = Bs + (ra + 64) * 32 + p * 8;

  for (int k0 = 0; k0 < K; k0 += 32) {
    __syncthreads();
    g2l16(gA0 + k0, lA0);
    g2l16(gA1 + k0, lA1);
    g2l16(gB0 + k0, lB0);
    g2l16(gB1 + k0, lB1);
    __syncthreads();
    bf16x8 af[4], bfr[4];
    #pragma unroll
    for (int fm = 0; fm < 4; fm++) {
      int r = wm + fm * 16 + lr;
      af[fm] = *(const bf16x8*)&As[r * 32 + ((quad ^ ((r >> 1) & 3)) << 3)];
    }
    #pragma unroll
    for (int fn = 0; fn < 4; fn++) {
      int r = wn + fn * 16 + lr;
      bfr[fn] = *(const bf16x8*)&Bs[r * 32 + ((quad ^ ((r >> 1) & 3)) << 3)];
    }
    #pragma unroll
    for (int fm = 0; fm < 4; fm++)
      #pragma unroll
      for (int fn = 0; fn < 4; fn++)
        acc[fm][fn] = __builtin_amdgcn_mfma_f32_16x16x32_bf16(
            af[fm], bfr[fn], acc[fm][fn], 0, 0, 0);
  }
}

#define GEMM_PRE()                                              \
  const int t = threadIdx.x;                                    \
  const int w = t >> 6, l = t & 63, quad = l >> 4, lr = l & 15; \
  const int wm = (w >> 1) * 64, wn = (w & 1) * 64;              \
  (void)w; (void)wm; (void)wn; (void)l;                         \
  f32x4 acc[4][4];                                              \
  { f32x4 z = {0.f, 0.f, 0.f, 0.f};                             \
    for (int i_ = 0; i_ < 4; i_++)                              \
      for (int j_ = 0; j_ < 4; j_++) acc[i_][j_] = z; }

// ===========================================================================
// Phase unit bodies (shared by the 5-dispatch path and the mega-kernel)
// ===========================================================================

// prep: [0,512) qk-weight cvt | [512,576) WvT transpose-cvt | [576,578) bias2
//       | [578,706) gn stats | [706,962) proj_w cvt
__device__ __forceinline__ void prep_unit(int u,
    const float* __restrict__ qkv_w, const float* __restrict__ proj_w,
    const float* __restrict__ qkv_b, const float* __restrict__ x,
    u16* __restrict__ wqk16, u16* __restrict__ wvT16, u16* __restrict__ pw16,
    float* __restrict__ bias2, float* __restrict__ stats,
    u16* lds, float* redf) {
  int t = threadIdx.x;
  if (u < 512) {                       // q,k weights: 131072 float4 exact
    int i = u * 256 + t;
    float4 v = ((const float4*)qkv_w)[i];
    u16x4 o;
    o.x = f2b(v.x); o.y = f2b(v.y); o.z = f2b(v.z); o.w = f2b(v.w);
    ((u16x4*)wqk16)[i] = o;
  } else if (u < 576) {                // WvT[d][c] = Wv[c][d] bf16
    u16 (*T)[68] = (u16(*)[68])lds;
    int tile = u - 512, tx = tile & 7, ty = tile >> 3;
    int row = t >> 4, col4 = t & 15;
    #pragma unroll
    for (int it = 0; it < 4; it++) {
      int cc = row + it * 16;
      float4 v = *(const float4*)&qkv_w[(size_t)(1024 + ty * 64 + cc) * 512 + tx * 64 + col4 * 4];
      u16x4 o;
      o.x = f2b(v.x); o.y = f2b(v.y); o.z = f2b(v.z); o.w = f2b(v.w);
      *(u16x4*)&T[cc][col4 * 4] = o;
    }
    __syncthreads();
    #pragma unroll
    for (int it = 0; it < 2; it++) {
      int ch = t + it * 256;
      int d = ch >> 3, c8 = (ch & 7) * 8;
      u16x8 o;
      #pragma unroll
      for (int j = 0; j < 8; j++) o[j] = T[c8 + j][d];
      *(u16x8*)&wvT16[(size_t)(tx * 64 + d) * 512 + ty * 64 + c8] = o;
    }
  } else if (u < 578) {                // bias2 = proj_w @ v_bias (fp32)
    int m = (u - 576) * 256 + t;
    float s = 0.f;
    for (int c = 0; c < 512; c++)
      s += proj_w[(size_t)m * 512 + c] * qkv_b[1024 + c];
    bias2[m] = s;
  } else if (u < 706) {                // gn stats: one (b,group) per unit
    int bg = u - 578;
    const float4* xp = (const float4*)(x + (size_t)bg * (CPG * Nn));
    float s = 0.f, ss = 0.f;
    const int cnt4 = CPG * Nn / 4;
    for (int i = t; i < cnt4; i += 256) {
      float4 v = xp[i];
      s  += v.x + v.y + v.z + v.w;
      ss += v.x * v.x + v.y * v.y + v.z * v.z + v.w * v.w;
    }
    #pragma unroll
    for (int off = 32; off > 0; off >>= 1) {
      s  += __shfl_down(s, off);
      ss += __shfl_down(ss, off);
    }
    int lane = t & 63, wid = t >> 6;
    if (lane == 0) { redf[wid] = s; redf[4 + wid] = ss; }
    __syncthreads();
    if (t == 0) {
      float S  = redf[0] + redf[1] + redf[2] + redf[3];
      float SS = redf[4] + redf[5] + redf[6] + redf[7];
      const float inv = 1.0f / (float)(CPG * Nn);
      float m = S * inv;
      float var = SS * inv - m * m;
      stats[bg]       = m;
      stats[128 + bg] = rsqrtf(var + EPSf);
    }
  } else {                             // proj_w cvt: 65536 float4
    int i = (u - 706) * 256 + t;
    float4 v = ((const float4*)proj_w)[i];
    u16x4 o;
    o.x = f2b(v.x); o.y = f2b(v.y); o.z = f2b(v.z); o.w = f2b(v.w);
    ((u16x4*)pw16)[i] = o;
  }
}

// gnw2: [0,16) W2 = pw16 @ Wv (via wvT16) | [16,2064) gn apply+transpose
__device__ __forceinline__ void gnw2_unit(int u, const float* __restrict__ x,
    const float* __restrict__ stats, const float* __restrict__ nw,
    const float* __restrict__ nb, const u16* __restrict__ pw16,
    const u16* __restrict__ wvT16, u16* __restrict__ W2, u16* __restrict__ hT,
    u16* AsBs) {
  if (u < 16) {
    int m0 = (u >> 2) * 128, d0 = (u & 3) * 128;
    GEMM_PRE();
    gemm_core(AsBs, AsBs + 4096, pw16 + (size_t)m0 * 512, 512,
              wvT16 + (size_t)d0 * 512, 512, 512, acc);
    #pragma unroll
    for (int fm = 0; fm < 4; fm++) {
      int m = m0 + wm + fm * 16 + quad * 4;
      #pragma unroll
      for (int fn = 0; fn < 4; fn++) {
        int d = d0 + wn + fn * 16 + lr;
        f32x4 a = acc[fm][fn];
        W2[(size_t)(m    ) * 512 + d] = f2b(a[0]);
        W2[(size_t)(m + 1) * 512 + d] = f2b(a[1]);
        W2[(size_t)(m + 2) * 512 + d] = f2b(a[2]);
        W2[(size_t)(m + 3) * 512 + d] = f2b(a[3]);
      }
    }
    return;
  }
  int u2 = u - 16;                     // 2048 tiles: 64c x 64n
  int b = u2 >> 7, rem = u2 & 127, c0 = (rem >> 4) * 64, n0 = (rem & 15) * 64;
  u16 (*T)[68] = (u16(*)[68])AsBs;
  int t = threadIdx.x;
  int row = t >> 4, col4 = t & 15;
  #pragma unroll
  for (int it = 0; it < 4; it++) {
    int cc = row + it * 16;
    int c  = c0 + cc;
    int bg = b * Gn + (c >> 6);
    float mean = stats[bg], rstd = stats[128 + bg];
    float a  = nw[c] * rstd;
    float bb = nb[c] - mean * a;
    float4 xv = *(const float4*)&x[((size_t)(b * Cn + c)) * Nn + n0 + col4 * 4];
    u16x4 o;
    o.x = f2b(xv.x * a + bb); o.y = f2b(xv.y * a + bb);
    o.z = f2b(xv.z * a + bb); o.w = f2b(xv.w * a + bb);
    *(u16x4*)&T[cc][col4 * 4] = o;
  }
  __syncthreads();
  #pragma unroll
  for (int it = 0; it < 2; it++) {
    int ch = t + it * 256;
    int n  = ch >> 3, c8 = (ch & 7) * 8;
    u16x8 o;
    #pragma unroll
    for (int j = 0; j < 8; j++) o[j] = T[c8 + j][n];
    *(u16x8*)&hT[((size_t)(b * Nn + n0 + n)) * 512 + c0 + c8] = o;
  }
}

// qkvp: [0,1024) qkT[b][n][m] = wqk.h + bias | [1024,1536) VP = W2 @ h
__device__ __forceinline__ void qkvp_unit(int u, const u16* __restrict__ wqk16,
    const u16* __restrict__ W2, const u16* __restrict__ hT,
    const float* __restrict__ qkv_b, u16* __restrict__ qkT,
    u16* __restrict__ VP, u16* AsBs) {
  GEMM_PRE();
  if (u < 1024) {
    int b = u >> 6, rem = u & 63, m0 = (rem >> 3) * 128, n0 = (rem & 7) * 128;
    gemm_core(AsBs, AsBs + 4096, wqk16 + (size_t)m0 * 512, 512,
              hT + ((size_t)(b * Nn + n0)) * 512, 512, 512, acc);
    #pragma unroll
    for (int fm = 0; fm < 4; fm++) {
      int mb = m0 + wm + fm * 16 + quad * 4;
      float b0 = qkv_b[mb], b1 = qkv_b[mb + 1], b2 = qkv_b[mb + 2], b3 = qkv_b[mb + 3];
      #pragma unroll
      for (int fn = 0; fn < 4; fn++) {
        int n = n0 + wn + fn * 16 + lr;
        f32x4 a = acc[fm][fn];
        u16x4 o;
        o.x = f2b(a[0] + b0); o.y = f2b(a[1] + b1);
        o.z = f2b(a[2] + b2); o.w = f2b(a[3] + b3);
        *(u16x4*)&qkT[((size_t)(b * Nn + n)) * 1024 + mb] = o;
      }
    }
  } else {
    int u2 = u - 1024;
    int b = u2 >> 5, rem = u2 & 31, m0 = (rem >> 3) * 128, j0 = (rem & 7) * 128;
    gemm_core(AsBs, AsBs + 4096, W2 + (size_t)m0 * 512, 512,
              hT + ((size_t)(b * Nn + j0)) * 512, 512, 512, acc);
    #pragma unroll
    for (int fm = 0; fm < 4; fm++) {
      int m = m0 + wm + fm * 16 + quad * 4;
      #pragma unroll
      for (int fn = 0; fn < 4; fn++) {
        int j = j0 + wn + fn * 16 + lr;
        f32x4 a = acc[fm][fn];
        VP[((size_t)(b * 512 + m    )) * 1024 + j] = f2b(a[0]);
        VP[((size_t)(b * 512 + m + 1)) * 1024 + j] = f2b(a[1]);
        VP[((size_t)(b * 512 + m + 2)) * 1024 + j] = f2b(a[2]);
        VP[((size_t)(b * 512 + m + 3)) * 1024 + j] = f2b(a[3]);
      }
    }
  }
}

// qkexp: Pm = exp(scale*q.k) bf16 unnormalized; rpart partial row sums.
// No max subtraction: logits ~ N(0,1).
__device__ __forceinline__ void qkexp_unit(int u, const u16* __restrict__ qkT,
    u16* __restrict__ Pm, float* __restrict__ rpart, u16* AsBs, float* psum) {
  int b = u >> 6, rem = u & 63, i0 = (rem >> 3) * 128, j0 = (rem & 7) * 128;
  const u16* base = qkT + (size_t)b * Nn * 1024;
  GEMM_PRE();
  gemm_core(AsBs, AsBs + 4096, base + (size_t)i0 * 1024, 1024,
            base + (size_t)j0 * 1024 + 512, 1024, 512, acc);
  if (t < 128) psum[t] = 0.f;
  __syncthreads();
  const float scale = 0.04419417382415922f;  // 512^-0.5
  #pragma unroll
  for (int fm = 0; fm < 4; fm++) {
    int ri = wm + fm * 16 + quad * 4;
    float rs0 = 0.f, rs1 = 0.f, rs2 = 0.f, rs3 = 0.f;
    #pragma unroll
    for (int fn = 0; fn < 4; fn++) {
      int j = j0 + wn + fn * 16 + lr;
      f32x4 a = acc[fm][fn];
      float p0 = __expf(a[0] * scale);
      float p1 = __expf(a[1] * scale);
      float p2 = __expf(a[2] * scale);
      float p3 = __expf(a[3] * scale);
      u16* Pp = &Pm[((size_t)(b * Nn + i0 + ri)) * 1024 + j];
      Pp[0]    = f2b(p0);
      Pp[1024] = f2b(p1);
      Pp[2048] = f2b(p2);
      Pp[3072] = f2b(p3);
      rs0 += p0; rs1 += p1; rs2 += p2; rs3 += p3;
    }
    #pragma unroll
    for (int mask = 1; mask < 16; mask <<= 1) {
      rs0 += __shfl_xor(rs0, mask);
      rs1 += __shfl_xor(rs1, mask);
      rs2 += __shfl_xor(rs2, mask);
      rs3 += __shfl_xor(rs3, mask);
    }
    if (lr == 0) {
      atomicAdd(&psum[ri],     rs0);
      atomicAdd(&psum[ri + 1], rs1);
      atomicAdd(&psum[ri + 2], rs2);
      atomicAdd(&psum[ri + 3], rs3);
    }
  }
  __syncthreads();
  if (t < 128)
    rpart[((size_t)(b * 8) + (rem & 7)) * 1024 + i0 + t] = psum[t];
}

// pvout: out = (VP @ Pm^T)/r + bias2 + proj_b + x
__device__ __forceinline__ void pvout_unit(int u, const u16* __restrict__ VP,
    const u16* __restrict__ Pm, const float* __restrict__ rpart,
    const float* __restrict__ bias2, const float* __restrict__ proj_b,
    const float* __restrict__ x, float* __restrict__ out,
    u16* AsBs, float* rinv) {
  int b = u >> 5, rem = u & 31, m0 = (rem >> 3) * 128, i0 = (rem & 7) * 128;
  if (threadIdx.x < 128) {
    float s = 0.f;
    #pragma unroll
    for (int jb = 0; jb < 8; jb++)
      s += rpart[((size_t)(b * 8 + jb)) * 1024 + i0 + threadIdx.x];
    rinv[threadIdx.x] = 1.0f / s;
  }
  GEMM_PRE();
  gemm_core(AsBs, AsBs + 4096, VP + ((size_t)(b * 512 + m0)) * 1024, 1024,
            Pm + ((size_t)(b * Nn + i0)) * 1024, 1024, 1024, acc);
  #pragma unroll
  for (int fm = 0; fm < 4; fm++) {
    int m = m0 + wm + fm * 16 + quad * 4;
    float c0 = bias2[m    ] + proj_b[m    ];
    float c1 = bias2[m + 1] + proj_b[m + 1];
    float c2 = bias2[m + 2] + proj_b[m + 2];
    float c3 = bias2[m + 3] + proj_b[m + 3];
    #pragma unroll
    for (int fn = 0; fn < 4; fn++) {
      int il = wn + fn * 16 + lr;
      int i  = i0 + il;
      float ri = rinv[il];
      f32x4 a = acc[fm][fn];
      size_t o0 = ((size_t)(b * Cn + m)) * Nn + i;
      out[o0                  ] = a[0] * ri + c0 + x[o0                  ];
      out[o0 + Nn             ] = a[1] * ri + c1 + x[o0 + Nn             ];
      out[o0 + 2 * Nn         ] = a[2] * ri + c2 + x[o0 + 2 * Nn         ];
      out[o0 + 3 * (size_t)Nn] = a[3] * ri + c3 + x[o0 + 3 * (size_t)Nn];
    }
  }
}

// ===========================================================================
// Standalone kernels (proven round-7 path)
// ===========================================================================
__global__ __launch_bounds__(256) void prep_k(const float* qkv_w,
    const float* proj_w, const float* qkv_b, const float* x, u16* wqk16,
    u16* wvT16, u16* pw16, float* bias2, float* stats) {
  __shared__ u16 lds[4352];
  __shared__ float redf[8];
  prep_unit(blockIdx.x, qkv_w, proj_w, qkv_b, x, wqk16, wvT16, pw16, bias2,
            stats, lds, redf);
}

__global__ __launch_bounds__(256) void gnw2_k(const float* x,
    const float* stats, const float* nw, const float* nb, const u16* pw16,
    const u16* wvT16, u16* W2, u16* hT) {
  __shared__ u16 AsBs[8192];
  gnw2_unit(blockIdx.x, x, stats, nw, nb, pw16, wvT16, W2, hT, AsBs);
}

__global__ __launch_bounds__(256) void qkvp_k(const u16* wqk16, const u16* W2,
    const u16* hT, const float* qkv_b, u16* qkT, u16* VP) {
  __shared__ u16 AsBs[8192];
  qkvp_unit(blockIdx.x, wqk16, W2, hT, qkv_b, qkT, VP, AsBs);
}

__global__ __launch_bounds__(256) void qkexp_k(const u16* qkT, u16* Pm,
                                               float* rpart) {
  __shared__ u16 AsBs[8192];
  __shared__ float psum[128];
  qkexp_unit(blockIdx.x, qkT, Pm, rpart, AsBs, psum);
}

__global__ __launch_bounds__(256) void pvout_k(const u16* VP, const u16* Pm,
    const float* rpart, const float* bias2, const float* proj_b,
    const float* x, float* out) {
  __shared__ u16 AsBs[8192];
  __shared__ float rinv[128];
  pvout_unit(blockIdx.x, VP, Pm, rpart, bias2, proj_b, x, out, AsBs, rinv);
}

// ===========================================================================
// Cooperative mega-kernel: same phases, grid.sync() between them.
// ===========================================================================
__global__ __launch_bounds__(256, 2) void mega_k(
    const float* x, const float* norm_w, const float* norm_b,
    const float* qkv_w, const float* qkv_b, const float* proj_w,
    const float* proj_b, float* out,
    u16* wqk16, u16* wvT16, u16* pw16, u16* W2, float* bias2, float* stats,
    u16* hT, u16* qkT, u16* VP, u16* Pm, float* rpart) {
  cg::grid_group grd = cg::this_grid();
  __shared__ u16 AsBs[8192];
  __shared__ float redf[128];
  const int bid = blockIdx.x;

  for (int u = bid; u < 962; u += GRIDC) {
    __syncthreads();
    prep_unit(u, qkv_w, proj_w, qkv_b, x, wqk16, wvT16, pw16, bias2, stats,
              AsBs, redf);
  }
  grd.sync();
  for (int u = bid; u < 2064; u += GRIDC) {
    __syncthreads();
    gnw2_unit(u, x, stats, norm_w, norm_b, pw16, wvT16, W2, hT, AsBs);
  }
  grd.sync();
  for (int u = bid; u < 1536; u += GRIDC)
    qkvp_unit(u, wqk16, W2, hT, qkv_b, qkT, VP, AsBs);
  grd.sync();
  for (int u = bid; u < 1024; u += GRIDC)
    qkexp_unit(u, qkT, Pm, rpart, AsBs, redf);
  grd.sync();
  pvout_unit(bid, VP, Pm, rpart, bias2, proj_b, x, out, AsBs, redf);
}

// ===========================================================================
extern "C" void kernel_launch(void* const* d_in, const int* in_sizes, int n_in,
                              void* d_out, int out_size, void* d_ws, size_t ws_size,
                              hipStream_t stream) {
  const float* x      = (const float*)d_in[0];
  const float* norm_w = (const float*)d_in[1];
  const float* norm_b = (const float*)d_in[2];
  const float* qkv_w  = (const float*)d_in[3];
  const float* qkv_b  = (const float*)d_in[4];
  const float* proj_w = (const float*)d_in[5];
  const float* proj_b = (const float*)d_in[6];
  float* out = (float*)d_out;
  char* ws = (char*)d_ws;

  u16*   wqk16 = (u16*)(ws);                     // 1024x512
  u16*   wvT16 = (u16*)(ws + 1048576);           // 512x512 (Wv^T)
  u16*   pw16  = (u16*)(ws + 1572864);           // 512x512
  u16*   W2    = (u16*)(ws + 2097152);           // 512x512 (= proj_w @ Wv)
  float* bias2 = (float*)(ws + 2621440);         // 512
  float* stats = (float*)(ws + 2623488);         // 256 (mean|rstd)
  u16*   hT    = (u16*)(ws + 2624512);           // B*N*C
  u16*   qkT   = (u16*)(ws + 19401728);          // B*N*1024
  u16*   VP    = (u16*)(ws + 52956160);          // B*512*N
  u16*   Pm    = (u16*)(ws + 69733376);          // B*N*N
  float* rpart = (float*)(ws + 103287808);       // B*8*N

  // Gate the cooperative path on host-side queries (capture-safe, no enqueue).
  int dev = 0;
  (void)hipGetDevice(&dev);
  int coopAttr = 0, nCU = 0, maxB = 0;
  (void)hipDeviceGetAttribute(&coopAttr, hipDeviceAttributeCooperativeLaunch, dev);
  (void)hipDeviceGetAttribute(&nCU, hipDeviceAttributeMultiprocessorCount, dev);
  (void)hipOccupancyMaxActiveBlocksPerMultiprocessor(&maxB, (const void*)mega_k,
                                                     256, 0);
  hipError_t err = hipErrorUnknown;
  if (coopAttr && maxB > 0 && (long)maxB * nCU >= GRIDC) {
    void* args[] = {
      (void*)&x, (void*)&norm_w, (void*)&norm_b, (void*)&qkv_w, (void*)&qkv_b,
      (void*)&proj_w, (void*)&proj_b, (void*)&out,
      (void*)&wqk16, (void*)&wvT16, (void*)&pw16, (void*)&W2, (void*)&bias2,
      (void*)&stats, (void*)&hT, (void*)&qkT, (void*)&VP, (void*)&Pm,
      (void*)&rpart,
    };
    err = hipLaunchCooperativeKernel((const void*)mega_k, dim3(GRIDC),
                                     dim3(256), args, 0, stream);
  }
  if (err != hipSuccess) {
    // Proven 5-dispatch fallback (round-7 path, identical unit bodies).
    prep_k<<<962, 256, 0, stream>>>(qkv_w, proj_w, qkv_b, x, wqk16, wvT16,
                                    pw16, bias2, stats);
    gnw2_k<<<2064, 256, 0, stream>>>(x, stats, norm_w, norm_b, pw16, wvT16,
                                     W2, hT);
    qkvp_k<<<1536, 256, 0, stream>>>(wqk16, W2, hT, qkv_b, qkT, VP);
    qkexp_k<<<1024, 256, 0, stream>>>(qkT, Pm, rpart);
    pvout_k<<<512, 256, 0, stream>>>(VP, Pm, rpart, bias2, proj_b, x, out);
  }
}

// Round 9
// 233.366 us; speedup vs baseline: 4.5054x; 1.0369x over previous
//
#include <hip/hip_runtime.h>
#include <math.h>

#define Bn   16
#define Cn   512
#define Nn   1024
#define Gn   8
#define CPG  64
#define EPSf 1e-5f

typedef short           bf16x8 __attribute__((ext_vector_type(8)));
typedef float           f32x4  __attribute__((ext_vector_type(4)));
typedef unsigned short  u16;
typedef unsigned short  u16x4  __attribute__((ext_vector_type(4)));
typedef unsigned short  u16x8  __attribute__((ext_vector_type(8)));

#define TS 136   // LDS repack row stride (u16): 272B rows, 16B-aligned, 2-way banks

__device__ __forceinline__ u16 f2b(float f) {
  union { float f; unsigned u; } c; c.f = f;
  unsigned r = (c.u + 0x7FFFu + ((c.u >> 16) & 1u)) >> 16;
  return (u16)r;
}

// async 16B global -> LDS DMA; LDS dest = wave-uniform base + lane*16
__device__ __forceinline__ void g2l16(const void* g, void* l) {
  __builtin_amdgcn_global_load_lds(
      (const __attribute__((address_space(1))) unsigned int*)g,
      (__attribute__((address_space(3))) unsigned int*)l, 16, 0, 0);
}

// GEMM core (BK=32, proven): D[128x128] = A[128xK]*B'[128xK]^T bf16.
// LDS unpadded 32-elem rows, chunk-XOR swizzle -> conflict-free ds_read_b128.
__device__ __forceinline__ void gemm_core(u16* As, u16* Bs,
    const u16* __restrict__ A, size_t sA,
    const u16* __restrict__ B, size_t sB, int K, f32x4 acc[4][4]) {
  const int t = threadIdx.x;
  const int w = t >> 6, l = t & 63, quad = l >> 4, lr = l & 15;
  const int wm = (w >> 1) * 64, wn = (w & 1) * 64;

  const int ra = w * 16 + (l >> 2);
  const int p  = l & 3;
  const int q  = p ^ ((ra >> 1) & 3);
  const u16* gA0 = A + (size_t)ra * sA + q * 8;
  const u16* gA1 = A + (size_t)(ra + 64) * sA + q * 8;
  const u16* gB0 = B + (size_t)ra * sB + q * 8;
  const u16* gB1 = B + (size_t)(ra + 64) * sB + q * 8;
  u16* lA0 = As + ra * 32 + p * 8;
  u16* lA1 = As + (ra + 64) * 32 + p * 8;
  u16* lB0 = Bs + ra * 32 + p * 8;
  u16* lB1 = Bs + (ra + 64) * 32 + p * 8;

  for (int k0 = 0; k0 < K; k0 += 32) {
    __syncthreads();
    g2l16(gA0 + k0, lA0);
    g2l16(gA1 + k0, lA1);
    g2l16(gB0 + k0, lB0);
    g2l16(gB1 + k0, lB1);
    __syncthreads();
    bf16x8 af[4], bfr[4];
    #pragma unroll
    for (int fm = 0; fm < 4; fm++) {
      int r = wm + fm * 16 + lr;
      af[fm] = *(const bf16x8*)&As[r * 32 + ((quad ^ ((r >> 1) & 3)) << 3)];
    }
    #pragma unroll
    for (int fn = 0; fn < 4; fn++) {
      int r = wn + fn * 16 + lr;
      bfr[fn] = *(const bf16x8*)&Bs[r * 32 + ((quad ^ ((r >> 1) & 3)) << 3)];
    }
    #pragma unroll
    for (int fm = 0; fm < 4; fm++)
      #pragma unroll
      for (int fn = 0; fn < 4; fn++)
        acc[fm][fn] = __builtin_amdgcn_mfma_f32_16x16x32_bf16(
            af[fm], bfr[fn], acc[fm][fn], 0, 0, 0);
  }
}

#define GEMM_PRE()                                              \
  const int t = threadIdx.x;                                    \
  const int w = t >> 6, l = t & 63, quad = l >> 4, lr = l & 15; \
  const int wm = (w >> 1) * 64, wn = (w & 1) * 64;              \
  (void)w; (void)wm; (void)wn; (void)l;                         \
  f32x4 acc[4][4];                                              \
  { f32x4 z = {0.f, 0.f, 0.f, 0.f};                             \
    for (int i_ = 0; i_ < 4; i_++)                              \
      for (int j_ = 0; j_ < 4; j_++) acc[i_][j_] = z; }

// coalesced LDS->global flush of a repacked 64x128 u16 tile (stride TS)
#define TILE_FLUSH(T, DST, rowstride)                           \
  {                                                             \
    _Pragma("unroll")                                           \
    for (int k_ = 0; k_ < 4; k_++) {                            \
      int idx = threadIdx.x + 256 * k_;                         \
      int row = idx >> 4, ch = idx & 15;                        \
      u16x8 v_ = *(u16x8*)&T[row * TS + ch * 8];                \
      *(u16x8*)&(DST)[(size_t)row * (rowstride) + ch * 8] = v_; \
    }                                                           \
  }

// ---------------------------------------------------------------------------
// prep: [0,512) qk-weight cvt | [512,576) WvT transpose-cvt | [576,578) bias2
//       | [578,1090) gn-stats partial raw sums (atomic) | [1090,1346) proj_w cvt
__global__ __launch_bounds__(256) void prep_k(const float* __restrict__ qkv_w,
    const float* __restrict__ proj_w, const float* __restrict__ qkv_b,
    const float* __restrict__ x, u16* __restrict__ wqk16,
    u16* __restrict__ wvT16, u16* __restrict__ pw16,
    float* __restrict__ bias2, float* __restrict__ stats) {
  __shared__ u16 T[64][68];
  __shared__ float redf[8];
  int bid = blockIdx.x, t = threadIdx.x;
  if (bid < 512) {                       // q,k weights: 131072 float4 exact
    int i = bid * 256 + t;
    float4 v = ((const float4*)qkv_w)[i];
    u16x4 o;
    o.x = f2b(v.x); o.y = f2b(v.y); o.z = f2b(v.z); o.w = f2b(v.w);
    ((u16x4*)wqk16)[i] = o;
  } else if (bid < 576) {                // WvT[d][c] = Wv[c][d] bf16
    int tile = bid - 512, tx = tile & 7, ty = tile >> 3;
    int row = t >> 4, col4 = t & 15;
    #pragma unroll
    for (int it = 0; it < 4; it++) {
      int cc = row + it * 16;
      float4 v = *(const float4*)&qkv_w[(size_t)(1024 + ty * 64 + cc) * 512 + tx * 64 + col4 * 4];
      u16x4 o;
      o.x = f2b(v.x); o.y = f2b(v.y); o.z = f2b(v.z); o.w = f2b(v.w);
      *(u16x4*)&T[cc][col4 * 4] = o;
    }
    __syncthreads();
    #pragma unroll
    for (int it = 0; it < 2; it++) {
      int ch = t + it * 256;
      int d = ch >> 3, c8 = (ch & 7) * 8;
      u16x8 o;
      #pragma unroll
      for (int j = 0; j < 8; j++) o[j] = T[c8 + j][d];
      *(u16x8*)&wvT16[(size_t)(tx * 64 + d) * 512 + ty * 64 + c8] = o;
    }
  } else if (bid < 578) {                // bias2 = proj_w @ v_bias (fp32 exact)
    int m = (bid - 576) * 256 + t;
    float s = 0.f;
    for (int c = 0; c < 512; c++)
      s += proj_w[(size_t)m * 512 + c] * qkv_b[1024 + c];
    bias2[m] = s;
  } else if (bid < 1090) {               // gn raw-sum partials: 4 blocks/(b,g)
    int idx = bid - 578, bg = idx >> 2, part = idx & 3;
    const float4* xp = (const float4*)x + (size_t)bg * 16384 + part * 4096;
    float s = 0.f, ss = 0.f;
    for (int i = t; i < 4096; i += 256) {
      float4 v = xp[i];
      s  += v.x + v.y + v.z + v.w;
      ss += v.x * v.x + v.y * v.y + v.z * v.z + v.w * v.w;
    }
    #pragma unroll
    for (int off = 32; off > 0; off >>= 1) {
      s  += __shfl_down(s, off);
      ss += __shfl_down(ss, off);
    }
    int lane = t & 63, wid = t >> 6;
    if (lane == 0) { redf[wid] = s; redf[4 + wid] = ss; }
    __syncthreads();
    if (t == 0) {
      atomicAdd(&stats[bg],       redf[0] + redf[1] + redf[2] + redf[3]);
      atomicAdd(&stats[128 + bg], redf[4] + redf[5] + redf[6] + redf[7]);
    }
  } else {                               // proj_w cvt: 65536 float4
    int i = (bid - 1090) * 256 + t;
    float4 v = ((const float4*)proj_w)[i];
    u16x4 o;
    o.x = f2b(v.x); o.y = f2b(v.y); o.z = f2b(v.z); o.w = f2b(v.w);
    ((u16x4*)pw16)[i] = o;
  }
}

// ---------------------------------------------------------------------------
// gnw2: [0,16) W2 = pw16 @ Wv | [16,2064) gn apply+transpose (raw-sum stats)
__global__ __launch_bounds__(256) void gnw2_k(const float* __restrict__ x,
    const float* __restrict__ stats, const float* __restrict__ nw,
    const float* __restrict__ nb, const u16* __restrict__ pw16,
    const u16* __restrict__ wvT16, u16* __restrict__ W2, u16* __restrict__ hT) {
  __shared__ u16 AsBs[8192];
  int bid = blockIdx.x;
  if (bid < 16) {
    int m0 = (bid >> 2) * 128, d0 = (bid & 3) * 128;
    GEMM_PRE();
    gemm_core(AsBs, AsBs + 4096, pw16 + (size_t)m0 * 512, 512,
              wvT16 + (size_t)d0 * 512, 512, 512, acc);
    #pragma unroll
    for (int fm = 0; fm < 4; fm++) {
      int m = m0 + wm + fm * 16 + quad * 4;
      #pragma unroll
      for (int fn = 0; fn < 4; fn++) {
        int d = d0 + wn + fn * 16 + lr;
        f32x4 a = acc[fm][fn];
        W2[(size_t)(m    ) * 512 + d] = f2b(a[0]);
        W2[(size_t)(m + 1) * 512 + d] = f2b(a[1]);
        W2[(size_t)(m + 2) * 512 + d] = f2b(a[2]);
        W2[(size_t)(m + 3) * 512 + d] = f2b(a[3]);
      }
    }
    return;
  }
  int u = bid - 16;                      // 2048 tiles: 64c x 64n
  int b = u >> 7, rem = u & 127, c0 = (rem >> 4) * 64, n0 = (rem & 15) * 64;
  u16 (*T)[68] = (u16(*)[68])AsBs;
  int t = threadIdx.x;
  int row = t >> 4, col4 = t & 15;
  const float inv = 1.0f / 65536.0f;
  #pragma unroll
  for (int it = 0; it < 4; it++) {
    int cc = row + it * 16;
    int c  = c0 + cc;
    int bg = b * Gn + (c >> 6);
    float mean = stats[bg] * inv;
    float var  = stats[128 + bg] * inv - mean * mean;
    float rstd = rsqrtf(var + EPSf);
    float a  = nw[c] * rstd;
    float bb = nb[c] - mean * a;
    float4 xv = *(const float4*)&x[((size_t)(b * Cn + c)) * Nn + n0 + col4 * 4];
    u16x4 o;
    o.x = f2b(xv.x * a + bb); o.y = f2b(xv.y * a + bb);
    o.z = f2b(xv.z * a + bb); o.w = f2b(xv.w * a + bb);
    *(u16x4*)&T[cc][col4 * 4] = o;
  }
  __syncthreads();
  #pragma unroll
  for (int it = 0; it < 2; it++) {
    int ch = t + it * 256;
    int n  = ch >> 3, c8 = (ch & 7) * 8;
    u16x8 o;
    #pragma unroll
    for (int j = 0; j < 8; j++) o[j] = T[c8 + j][n];
    *(u16x8*)&hT[((size_t)(b * Nn + n0 + n)) * 512 + c0 + c8] = o;
  }
}

// ---------------------------------------------------------------------------
// qkvp: [0,1024) qkT[b][n][m] = wqk.h + bias (LDS-transposed, coalesced)
//       [1024,1536) VP = W2 @ h (LDS-repacked, coalesced)
__global__ __launch_bounds__(256) void qkvp_k(const u16* __restrict__ wqk16,
    const u16* __restrict__ W2, const u16* __restrict__ hT,
    const float* __restrict__ qkv_b, u16* __restrict__ qkT,
    u16* __restrict__ VP) {
  __shared__ u16 SH[64 * TS];            // >= 8192 for As/Bs, 8704 for repack
  int u = blockIdx.x;
  GEMM_PRE();
  if (u < 1024) {
    int b = u >> 6, rem = u & 63, m0 = (rem >> 3) * 128, n0 = (rem & 7) * 128;
    gemm_core(SH, SH + 4096, wqk16 + (size_t)m0 * 512, 512,
              hT + ((size_t)(b * Nn + n0)) * 512, 512, 512, acc);
    float bss[4][4];
    #pragma unroll
    for (int fm = 0; fm < 4; fm++) {
      int mb = m0 + wm + fm * 16 + quad * 4;
      #pragma unroll
      for (int r = 0; r < 4; r++) bss[fm][r] = qkv_b[mb + r];
    }
    // transpose-repack: half h covers n_local in [h*64, h*64+64)
    #pragma unroll
    for (int h = 0; h < 2; h++) {
      __syncthreads();
      if ((w & 1) == h) {                // these waves hold cols of this half
        #pragma unroll
        for (int fm = 0; fm < 4; fm++) {
          int mb = wm + fm * 16 + quad * 4;   // m_local, 4-aligned
          #pragma unroll
          for (int fn = 0; fn < 4; fn++) {
            int nl = fn * 16 + lr;            // n within half
            f32x4 a = acc[fm][fn];
            u16x4 pk;
            pk.x = f2b(a[0] + bss[fm][0]); pk.y = f2b(a[1] + bss[fm][1]);
            pk.z = f2b(a[2] + bss[fm][2]); pk.w = f2b(a[3] + bss[fm][3]);
            *(u16x4*)&SH[nl * TS + mb] = pk;  // T[n][m]
          }
        }
      }
      __syncthreads();
      u16* dst = qkT + ((size_t)(b * Nn + n0 + h * 64)) * 1024 + m0;
      TILE_FLUSH(SH, dst, 1024);
    }
  } else {
    int u2 = u - 1024;
    int b = u2 >> 5, rem = u2 & 31, m0 = (rem >> 3) * 128, j0 = (rem & 7) * 128;
    gemm_core(SH, SH + 4096, W2 + (size_t)m0 * 512, 512,
              hT + ((size_t)(b * Nn + j0)) * 512, 512, 512, acc);
    // natural repack: half h covers m_local in [h*64, h*64+64)
    #pragma unroll
    for (int h = 0; h < 2; h++) {
      __syncthreads();
      if ((w >> 1) == h) {               // these waves hold rows of this half
        #pragma unroll
        for (int fm = 0; fm < 4; fm++) {
          int ml = fm * 16 + quad * 4;        // m within half
          #pragma unroll
          for (int fn = 0; fn < 4; fn++) {
            int jl = wn + fn * 16 + lr;
            f32x4 a = acc[fm][fn];
            SH[(ml    ) * TS + jl] = f2b(a[0]);
            SH[(ml + 1) * TS + jl] = f2b(a[1]);
            SH[(ml + 2) * TS + jl] = f2b(a[2]);
            SH[(ml + 3) * TS + jl] = f2b(a[3]);
          }
        }
      }
      __syncthreads();
      u16* dst = VP + ((size_t)(b * 512 + m0 + h * 64)) * 1024 + j0;
      TILE_FLUSH(SH, dst, 1024);
    }
  }
}

// ---------------------------------------------------------------------------
// qkexp: Pm = exp(scale*q.k) bf16 unnormalized (LDS-repacked stores);
// rpart partial row sums. No max subtraction: logits ~ N(0,1).
__global__ __launch_bounds__(256) void qkexp_k(const u16* __restrict__ qkT,
    u16* __restrict__ Pm, float* __restrict__ rpart) {
  __shared__ u16 SH[64 * TS];
  __shared__ float psum[128];
  int u = blockIdx.x;
  int b = u >> 6, rem = u & 63, i0 = (rem >> 3) * 128, j0 = (rem & 7) * 128;
  const u16* base = qkT + (size_t)b * Nn * 1024;
  GEMM_PRE();
  gemm_core(SH, SH + 4096, base + (size_t)i0 * 1024, 1024,
            base + (size_t)j0 * 1024 + 512, 1024, 512, acc);
  if (t < 128) psum[t] = 0.f;
  __syncthreads();
  const float scale = 0.04419417382415922f;  // 512^-0.5
  #pragma unroll
  for (int fm = 0; fm < 4; fm++) {
    int ri = wm + fm * 16 + quad * 4;
    float rs0 = 0.f, rs1 = 0.f, rs2 = 0.f, rs3 = 0.f;
    #pragma unroll
    for (int fn = 0; fn < 4; fn++) {
      f32x4 a = acc[fm][fn];
      rs0 += __expf(a[0] * scale);
      rs1 += __expf(a[1] * scale);
      rs2 += __expf(a[2] * scale);
      rs3 += __expf(a[3] * scale);
    }
    #pragma unroll
    for (int mask = 1; mask < 16; mask <<= 1) {
      rs0 += __shfl_xor(rs0, mask);
      rs1 += __shfl_xor(rs1, mask);
      rs2 += __shfl_xor(rs2, mask);
      rs3 += __shfl_xor(rs3, mask);
    }
    if (lr == 0) {
      atomicAdd(&psum[ri],     rs0);
      atomicAdd(&psum[ri + 1], rs1);
      atomicAdd(&psum[ri + 2], rs2);
      atomicAdd(&psum[ri + 3], rs3);
    }
  }
  __syncthreads();
  if (t < 128)
    rpart[((size_t)(b * 8) + (rem & 7)) * 1024 + i0 + t] = psum[t];
  // natural repack + coalesced Pm stores
  #pragma unroll
  for (int h = 0; h < 2; h++) {
    __syncthreads();
    if ((w >> 1) == h) {
      #pragma unroll
      for (int fm = 0; fm < 4; fm++) {
        int il = fm * 16 + quad * 4;
        #pragma unroll
        for (int fn = 0; fn < 4; fn++) {
          int jl = wn + fn * 16 + lr;
          f32x4 a = acc[fm][fn];
          SH[(il    ) * TS + jl] = f2b(__expf(a[0] * scale));
          SH[(il + 1) * TS + jl] = f2b(__expf(a[1] * scale));
          SH[(il + 2) * TS + jl] = f2b(__expf(a[2] * scale));
          SH[(il + 3) * TS + jl] = f2b(__expf(a[3] * scale));
        }
      }
    }
    __syncthreads();
    u16* dst = Pm + ((size_t)(b * Nn + i0 + h * 64)) * 1024 + j0;
    TILE_FLUSH(SH, dst, 1024);
  }
}

// ---------------------------------------------------------------------------
// pvout: out = (VP @ Pm^T)/r + bias2 + proj_b + x
__global__ __launch_bounds__(256) void pvout_k(const u16* __restrict__ VP,
    const u16* __restrict__ Pm, const float* __restrict__ rpart,
    const float* __restrict__ bias2, const float* __restrict__ proj_b,
    const float* __restrict__ x, float* __restrict__ out) {
  __shared__ u16 AsBs[8192];
  __shared__ float rinv[128];
  int bid = blockIdx.x;
  int b = bid >> 5, rem = bid & 31, m0 = (rem >> 3) * 128, i0 = (rem & 7) * 128;
  if (threadIdx.x < 128) {
    float s = 0.f;
    #pragma unroll
    for (int jb = 0; jb < 8; jb++)
      s += rpart[((size_t)(b * 8 + jb)) * 1024 + i0 + threadIdx.x];
    rinv[threadIdx.x] = 1.0f / s;
  }
  GEMM_PRE();
  gemm_core(AsBs, AsBs + 4096, VP + ((size_t)(b * 512 + m0)) * 1024, 1024,
            Pm + ((size_t)(b * Nn + i0)) * 1024, 1024, 1024, acc);
  #pragma unroll
  for (int fm = 0; fm < 4; fm++) {
    int m = m0 + wm + fm * 16 + quad * 4;
    float c0 = bias2[m    ] + proj_b[m    ];
    float c1 = bias2[m + 1] + proj_b[m + 1];
    float c2 = bias2[m + 2] + proj_b[m + 2];
    float c3 = bias2[m + 3] + proj_b[m + 3];
    #pragma unroll
    for (int fn = 0; fn < 4; fn++) {
      int il = wn + fn * 16 + lr;
      int i  = i0 + il;
      float ri = rinv[il];
      f32x4 a = acc[fm][fn];
      size_t o0 = ((size_t)(b * Cn + m)) * Nn + i;
      out[o0                  ] = a[0] * ri + c0 + x[o0                  ];
      out[o0 + Nn             ] = a[1] * ri + c1 + x[o0 + Nn             ];
      out[o0 + 2 * Nn         ] = a[2] * ri + c2 + x[o0 + 2 * Nn         ];
      out[o0 + 3 * (size_t)Nn] = a[3] * ri + c3 + x[o0 + 3 * (size_t)Nn];
    }
  }
}

// ---------------------------------------------------------------------------
extern "C" void kernel_launch(void* const* d_in, const int* in_sizes, int n_in,
                              void* d_out, int out_size, void* d_ws, size_t ws_size,
                              hipStream_t stream) {
  const float* x      = (const float*)d_in[0];
  const float* norm_w = (const float*)d_in[1];
  const float* norm_b = (const float*)d_in[2];
  const float* qkv_w  = (const float*)d_in[3];
  const float* qkv_b  = (const float*)d_in[4];
  const float* proj_w = (const float*)d_in[5];
  const float* proj_b = (const float*)d_in[6];
  float* out = (float*)d_out;
  char* ws = (char*)d_ws;

  u16*   wqk16 = (u16*)(ws);                     // 1024x512
  u16*   wvT16 = (u16*)(ws + 1048576);           // 512x512 (Wv^T)
  u16*   pw16  = (u16*)(ws + 1572864);           // 512x512
  u16*   W2    = (u16*)(ws + 2097152);           // 512x512 (= proj_w @ Wv)
  float* bias2 = (float*)(ws + 2621440);         // 512
  float* stats = (float*)(ws + 2623488);         // 256 raw sums (memset to 0)
  u16*   hT    = (u16*)(ws + 2624512);           // B*N*C
  u16*   qkT   = (u16*)(ws + 19401728);          // B*N*1024
  u16*   VP    = (u16*)(ws + 52956160);          // B*512*N
  u16*   Pm    = (u16*)(ws + 69733376);          // B*N*N
  float* rpart = (float*)(ws + 103287808);       // B*8*N

  hipMemsetAsync(stats, 0, 1024, stream);
  prep_k<<<1346, 256, 0, stream>>>(qkv_w, proj_w, qkv_b, x, wqk16, wvT16,
                                   pw16, bias2, stats);
  gnw2_k<<<2064, 256, 0, stream>>>(x, stats, norm_w, norm_b, pw16, wvT16,
                                   W2, hT);
  qkvp_k<<<1536, 256, 0, stream>>>(wqk16, W2, hT, qkv_b, qkT, VP);
  qkexp_k<<<1024, 256, 0, stream>>>(qkT, Pm, rpart);
  pvout_k<<<512, 256, 0, stream>>>(VP, Pm, rpart, bias2, proj_b, x, out);
}